// Round 20
// baseline (97.242 us; speedup 1.0000x reference)
//
#include <hip/hip_runtime.h>
#include <hip/hip_bf16.h>

#define B_ 4
#define C_ 256
#define D_ 128
#define N_ 4096

typedef float f32x4 __attribute__((ext_vector_type(4)));
typedef short bf16x8 __attribute__((ext_vector_type(8)));
typedef short s16x4 __attribute__((ext_vector_type(4)));
typedef unsigned short u16;
typedef unsigned int u32;

__device__ __forceinline__ u16 f2bf(float f) {
  unsigned u = __float_as_uint(f);
  u += 0x7fffu + ((u >> 16) & 1u);
  return (u16)(u >> 16);
}
__device__ __forceinline__ float bf2f(u16 v) {
  return __uint_as_float(((u32)v) << 16);
}
// HW packed f32->bf16 (RNE): a -> low half, b -> high half (validated r8)
__device__ __forceinline__ u32 cvt_pk_bf16(float a, float b) {
  u32 r;
  asm("v_cvt_pk_bf16_f32 %0, %1, %2" : "=v"(r) : "v"(a), "v"(b));
  return r;
}

// ------ W cast: f32 -> hi/lo bf16 pair [3][128][256]; Wq pre-scaled by log2e
__global__ __launch_bounds__(256) void castw_kernel(
    const float* __restrict__ Wq, const float* __restrict__ Wk,
    const float* __restrict__ Wv, u16* __restrict__ Whi,
    u16* __restrict__ Wlo) {
  const int i = blockIdx.x * 256 + threadIdx.x;  // 24576 threads x 4 elems
  const int m = i >> 13;
  const int j = (i & 8191) * 4;
  const float* src = (m == 0) ? Wq : (m == 1) ? Wk : Wv;
  const float scale = (m == 0) ? 1.44269504f : 1.0f;  // fold log2(e) into Q
  const float4 v = *(const float4*)(src + j);
  const float vv[4] = {v.x * scale, v.y * scale, v.z * scale, v.w * scale};
  s16x4 h, l;
#pragma unroll
  for (int k = 0; k < 4; ++k) {
    const u16 hb = f2bf(vv[k]);
    h[k] = (short)hb;
    l[k] = (short)f2bf(vv[k] - bf2f(hb));
  }
  *(s16x4*)&Whi[m * 32768 + j] = h;
  *(s16x4*)&Wlo[m * 32768 + j] = l;
}

// ------- projection via 3-term hi/lo MFMA: Q/K -> [N][D], V -> [D][N] -------
// 4 independent accumulator chains (2 dt x 2 nt) hide MFMA latency; per-acc
// accumulation order identical to r17/r19 (bit-identical outputs).
__global__ __launch_bounds__(256, 2) void proj_kernel(
    const float* __restrict__ x, const u16* __restrict__ Whi,
    const u16* __restrict__ Wlo, u16* __restrict__ Qo, u16* __restrict__ Ko,
    u16* __restrict__ Vt) {
  __shared__ __align__(16) u16 xs_h[32 * 256];  // x^T hi [n][c], swizzled
  __shared__ __align__(16) u16 xs_l[32 * 256];  // x^T lo

  const int n0 = blockIdx.x * 32;
  const int b = blockIdx.y;
  const int t = threadIdx.x;
  const int w = t >> 6, lane = t & 63, g = lane >> 4, c = lane & 15;

  {
    const float* xb = x + ((size_t)b * C_) * N_ + n0;
#pragma unroll
    for (int r = 0; r < 8; ++r) {
      const int id = r * 256 + t;
      const int cr = id >> 3, nq = (id & 7) * 4;
      const float4 v = *(const float4*)(xb + (size_t)cr * N_ + nq);
      const u32 h01 = cvt_pk_bf16(v.x, v.y);
      const u32 h23 = cvt_pk_bf16(v.z, v.w);
      const float r0 = v.x - bf2f((u16)(h01 & 0xffffu));
      const float r1 = v.y - bf2f((u16)(h01 >> 16));
      const float r2 = v.z - bf2f((u16)(h23 & 0xffffu));
      const float r3 = v.w - bf2f((u16)(h23 >> 16));
      const u32 l01 = cvt_pk_bf16(r0, r1);
      const u32 l23 = cvt_pk_bf16(r2, r3);
      const u16 hv[4] = {(u16)(h01 & 0xffffu), (u16)(h01 >> 16),
                         (u16)(h23 & 0xffffu), (u16)(h23 >> 16)};
      const u16 lv[4] = {(u16)(l01 & 0xffffu), (u16)(l01 >> 16),
                         (u16)(l23 & 0xffffu), (u16)(l23 >> 16)};
#pragma unroll
      for (int k2 = 0; k2 < 4; ++k2) {
        const int idx2 = (nq + k2) * 256 + (cr ^ (((nq + k2) & 7) << 3));
        xs_h[idx2] = hv[k2];
        xs_l[idx2] = lv[k2];
      }
    }
  }
  __syncthreads();

  if (w < 2) {
    // Q (w=0) / K (w=1): 8 dt tiles, processed in pairs with 4 acc chains
    const size_t wo = (size_t)w * 32768;
    u16* __restrict__ O = (w == 0 ? Qo : Ko) + (size_t)b * N_ * D_;
#pragma unroll 1
    for (int dtg = 0; dtg < 4; ++dtg) {
      f32x4 a00 = {0.f, 0.f, 0.f, 0.f};  // [dt0][nt0]
      f32x4 a01 = {0.f, 0.f, 0.f, 0.f};  // [dt0][nt1]
      f32x4 a10 = {0.f, 0.f, 0.f, 0.f};  // [dt1][nt0]
      f32x4 a11 = {0.f, 0.f, 0.f, 0.f};  // [dt1][nt1]
      const int dt0 = dtg * 2, dt1 = dtg * 2 + 1;
#pragma unroll 1
      for (int kcb = 0; kcb < 2; ++kcb) {
        bf16x8 w0h[4], w0l[4], w1h[4], w1l[4];
#pragma unroll
        for (int j = 0; j < 4; ++j) {
          const size_t o0 = wo + (size_t)(dt0 * 16 + c) * 256 +
                            (kcb * 4 + j) * 32 + g * 8;
          const size_t o1 = wo + (size_t)(dt1 * 16 + c) * 256 +
                            (kcb * 4 + j) * 32 + g * 8;
          w0h[j] = *(const bf16x8*)&Whi[o0];
          w0l[j] = *(const bf16x8*)&Wlo[o0];
          w1h[j] = *(const bf16x8*)&Whi[o1];
          w1l[j] = *(const bf16x8*)&Wlo[o1];
        }
#pragma unroll
        for (int j = 0; j < 4; ++j) {
          const int kc = kcb * 4 + j;
          const int col = (kc * 32 + g * 8) ^ ((c & 7) << 3);
          const bf16x8 xh0 = *(const bf16x8*)&xs_h[c * 256 + col];
          const bf16x8 xl0 = *(const bf16x8*)&xs_l[c * 256 + col];
          const bf16x8 xh1 = *(const bf16x8*)&xs_h[(16 + c) * 256 + col];
          const bf16x8 xl1 = *(const bf16x8*)&xs_l[(16 + c) * 256 + col];
          // 12 MFMA across 4 independent chains (distance 4 hides latency)
          a00 = __builtin_amdgcn_mfma_f32_16x16x32_bf16(xh0, w0h[j], a00, 0, 0, 0);
          a01 = __builtin_amdgcn_mfma_f32_16x16x32_bf16(xh1, w0h[j], a01, 0, 0, 0);
          a10 = __builtin_amdgcn_mfma_f32_16x16x32_bf16(xh0, w1h[j], a10, 0, 0, 0);
          a11 = __builtin_amdgcn_mfma_f32_16x16x32_bf16(xh1, w1h[j], a11, 0, 0, 0);
          a00 = __builtin_amdgcn_mfma_f32_16x16x32_bf16(xh0, w0l[j], a00, 0, 0, 0);
          a01 = __builtin_amdgcn_mfma_f32_16x16x32_bf16(xh1, w0l[j], a01, 0, 0, 0);
          a10 = __builtin_amdgcn_mfma_f32_16x16x32_bf16(xh0, w1l[j], a10, 0, 0, 0);
          a11 = __builtin_amdgcn_mfma_f32_16x16x32_bf16(xh1, w1l[j], a11, 0, 0, 0);
          a00 = __builtin_amdgcn_mfma_f32_16x16x32_bf16(xl0, w0h[j], a00, 0, 0, 0);
          a01 = __builtin_amdgcn_mfma_f32_16x16x32_bf16(xl1, w0h[j], a01, 0, 0, 0);
          a10 = __builtin_amdgcn_mfma_f32_16x16x32_bf16(xl0, w1h[j], a10, 0, 0, 0);
          a11 = __builtin_amdgcn_mfma_f32_16x16x32_bf16(xl1, w1h[j], a11, 0, 0, 0);
        }
      }
#pragma unroll
      for (int i = 0; i < 4; ++i) {
        O[(size_t)(n0 + g * 4 + i) * D_ + dt0 * 16 + c] = f2bf(a00[i]);
        O[(size_t)(n0 + 16 + g * 4 + i) * D_ + dt0 * 16 + c] = f2bf(a01[i]);
        O[(size_t)(n0 + g * 4 + i) * D_ + dt1 * 16 + c] = f2bf(a10[i]);
        O[(size_t)(n0 + 16 + g * 4 + i) * D_ + dt1 * 16 + c] = f2bf(a11[i]);
      }
    }
  } else {
    // V (w=2,3): 4 dt tiles each, processed in pairs with 4 acc chains
    const size_t wo = (size_t)2 * 32768;
    const int dbase = (w - 2) * 64;
    u16* __restrict__ O = Vt + (size_t)b * D_ * N_;
#pragma unroll 1
    for (int dtg = 0; dtg < 2; ++dtg) {
      f32x4 a00 = {0.f, 0.f, 0.f, 0.f};
      f32x4 a01 = {0.f, 0.f, 0.f, 0.f};
      f32x4 a10 = {0.f, 0.f, 0.f, 0.f};
      f32x4 a11 = {0.f, 0.f, 0.f, 0.f};
      const int dr0 = dbase + dtg * 32, dr1 = dbase + dtg * 32 + 16;
#pragma unroll 1
      for (int kcb = 0; kcb < 2; ++kcb) {
        bf16x8 w0h[4], w0l[4], w1h[4], w1l[4];
#pragma unroll
        for (int j = 0; j < 4; ++j) {
          const size_t o0 =
              wo + (size_t)(dr0 + c) * 256 + (kcb * 4 + j) * 32 + g * 8;
          const size_t o1 =
              wo + (size_t)(dr1 + c) * 256 + (kcb * 4 + j) * 32 + g * 8;
          w0h[j] = *(const bf16x8*)&Whi[o0];
          w0l[j] = *(const bf16x8*)&Wlo[o0];
          w1h[j] = *(const bf16x8*)&Whi[o1];
          w1l[j] = *(const bf16x8*)&Wlo[o1];
        }
#pragma unroll
        for (int j = 0; j < 4; ++j) {
          const int kc = kcb * 4 + j;
          const int col = (kc * 32 + g * 8) ^ ((c & 7) << 3);
          const bf16x8 xh0 = *(const bf16x8*)&xs_h[c * 256 + col];
          const bf16x8 xl0 = *(const bf16x8*)&xs_l[c * 256 + col];
          const bf16x8 xh1 = *(const bf16x8*)&xs_h[(16 + c) * 256 + col];
          const bf16x8 xl1 = *(const bf16x8*)&xs_l[(16 + c) * 256 + col];
          a00 = __builtin_amdgcn_mfma_f32_16x16x32_bf16(w0h[j], xh0, a00, 0, 0, 0);
          a01 = __builtin_amdgcn_mfma_f32_16x16x32_bf16(w0h[j], xh1, a01, 0, 0, 0);
          a10 = __builtin_amdgcn_mfma_f32_16x16x32_bf16(w1h[j], xh0, a10, 0, 0, 0);
          a11 = __builtin_amdgcn_mfma_f32_16x16x32_bf16(w1h[j], xh1, a11, 0, 0, 0);
          a00 = __builtin_amdgcn_mfma_f32_16x16x32_bf16(w0l[j], xh0, a00, 0, 0, 0);
          a01 = __builtin_amdgcn_mfma_f32_16x16x32_bf16(w0l[j], xh1, a01, 0, 0, 0);
          a10 = __builtin_amdgcn_mfma_f32_16x16x32_bf16(w1l[j], xh0, a10, 0, 0, 0);
          a11 = __builtin_amdgcn_mfma_f32_16x16x32_bf16(w1l[j], xh1, a11, 0, 0, 0);
          a00 = __builtin_amdgcn_mfma_f32_16x16x32_bf16(w0h[j], xl0, a00, 0, 0, 0);
          a01 = __builtin_amdgcn_mfma_f32_16x16x32_bf16(w0h[j], xl1, a01, 0, 0, 0);
          a10 = __builtin_amdgcn_mfma_f32_16x16x32_bf16(w1h[j], xl0, a10, 0, 0, 0);
          a11 = __builtin_amdgcn_mfma_f32_16x16x32_bf16(w1h[j], xl1, a11, 0, 0, 0);
        }
      }
#pragma unroll
      for (int i = 0; i < 4; ++i) {
        O[(size_t)(dr0 + g * 4 + i) * N_ + n0 + c] = f2bf(a00[i]);
        O[(size_t)(dr0 + g * 4 + i) * N_ + n0 + 16 + c] = f2bf(a01[i]);
        O[(size_t)(dr1 + g * 4 + i) * N_ + n0 + c] = f2bf(a10[i]);
        O[(size_t)(dr1 + g * 4 + i) * N_ + n0 + 16 + c] = f2bf(a11[i]);
      }
    }
  }
}

// swizzled LDS index helpers (u16 units)
__device__ __forceinline__ int kIdx(int row, int col) {
  return row * 128 + (col ^ ((row & 7) << 3));
}
__device__ __forceinline__ int vIdx(int d, int col) {
  return d * 64 + (col ^ ((d & 7) << 3));
}
// V k-column permutation (validated end-to-end in rounds 6/12-19)
__device__ __forceinline__ int kprm(int q) {
  const int ct = q >> 2, qq = q & 3;
  return ((ct >> 1) << 5) +
         (((qq >> 1) == (ct & 1)) ? (qq << 3) : (((qq ^ 2) << 3) + 4));
}

// -------- flash attention (split-K), 32 q-rows/wave, KVBLK=128 pairs --------
// (round-17 body, unchanged: best measured 59.7 us)
__global__ __launch_bounds__(256, 2) void attn_kernel(
    const u16* __restrict__ Q, const u16* __restrict__ K,
    const u16* __restrict__ Vt, u16* __restrict__ op,
    float* __restrict__ mb, float* __restrict__ lb,
    float* __restrict__ outf, int qt, int rem, int S) {
  __shared__ __align__(16) u16 lds_k[2][64 * 128];   // [slot][kpos][d]
  __shared__ __align__(16) u16 lds_vt[2][128 * 64];  // [slot][d][k']

  const int L = blockIdx.x;
  int qx, b, sid;
  if (((B_ * S) & 7) == 0) {
    const int gpx = (B_ * S) >> 3;
    const int xcd = L & 7, idx = L >> 3;
    const int grp = xcd * gpx + (idx >> 5);
    qx = idx & 31;
    b = grp / S;
    sid = grp - b * S;
  } else {
    qx = L & 31;
    const int r2 = L >> 5;
    b = r2 % B_;
    sid = r2 / B_;
  }
  const int q0 = qx * 128;
  const int NT = qt + (sid < rem ? 1 : 0);  // S in {4,2,1}: NT always even
  const int t0 = sid * qt + (sid < rem ? sid : rem);
  const int k0 = t0 * 64;
  const int t = threadIdx.x;
  const int w = t >> 6, lane = t & 63, g = lane >> 4, c = lane & 15;
  const int qw = q0 + w * 32;
  const bool ghi = (g & 2) != 0;

  const u16* __restrict__ Qb = Q + (size_t)b * N_ * D_;
  const u16* __restrict__ Kb = K + (size_t)b * N_ * D_;
  const u16* __restrict__ Vb = Vt + (size_t)b * D_ * N_;

  bf16x8 qf[2][4];
#pragma unroll
  for (int qh = 0; qh < 2; ++qh)
#pragma unroll
    for (int kc = 0; kc < 4; ++kc)
      qf[qh][kc] =
          *(const bf16x8*)&Qb[(size_t)(qw + qh * 16 + c) * D_ + kc * 32 + g * 8];

  f32x4 acc[8][2];
  f32x4 accl[2];
#pragma unroll
  for (int dt = 0; dt < 8; ++dt)
#pragma unroll
    for (int qh = 0; qh < 2; ++qh) acc[dt][qh] = (f32x4){0.f, 0.f, 0.f, 0.f};
  accl[0] = (f32x4){0.f, 0.f, 0.f, 0.f};
  accl[1] = (f32x4){0.f, 0.f, 0.f, 0.f};
  float mrow[2] = {-3.0e38f, -3.0e38f};
  const float THR = 11.5415603f;  // 8 * log2(e)

  bf16x8 onesv;
#pragma unroll
  for (int j = 0; j < 8; ++j) onesv[j] = (short)0x3F80;

  bf16x8 krg[8], vrg[8];
  auto load_pair = [&](int kbase) {
#pragma unroll
    for (int h = 0; h < 2; ++h)
#pragma unroll
      for (int i = 0; i < 4; ++i) {
        const int idx = i * 256 + t;
        const int kb2 = kbase + h * 64;
        krg[h * 4 + i] =
            *(const bf16x8*)&Kb[(size_t)(kb2 + (idx >> 4)) * D_ + (idx & 15) * 8];
        vrg[h * 4 + i] =
            *(const bf16x8*)&Vb[(size_t)(idx >> 3) * N_ + kb2 + (idx & 7) * 8];
      }
  };
  load_pair(k0);

  auto proc = [&](const u16* kb, const u16* vb) {
    f32x4 s[4][2];
#pragma unroll
    for (int ct = 0; ct < 4; ++ct)
#pragma unroll
      for (int qh = 0; qh < 2; ++qh) s[ct][qh] = (f32x4){0.f, 0.f, 0.f, 0.f};
    __builtin_amdgcn_s_setprio(1);
#pragma unroll
    for (int kc = 0; kc < 4; ++kc) {
#pragma unroll
      for (int ct = 0; ct < 4; ++ct) {
        const bf16x8 kf = *(const bf16x8*)&kb[kIdx(ct * 16 + c, kc * 32 + g * 8)];
        s[ct][0] = __builtin_amdgcn_mfma_f32_16x16x32_bf16(kf, qf[0][kc], s[ct][0], 0, 0, 0);
        s[ct][1] = __builtin_amdgcn_mfma_f32_16x16x32_bf16(kf, qf[1][kc], s[ct][1], 0, 0, 0);
      }
    }
    __builtin_amdgcn_s_setprio(0);

    float pml[2];
#pragma unroll
    for (int qh = 0; qh < 2; ++qh) {
      const float m0 = fmaxf(fmaxf(s[0][qh][0], s[0][qh][1]),
                             fmaxf(s[0][qh][2], s[0][qh][3]));
      const float m1 = fmaxf(fmaxf(s[1][qh][0], s[1][qh][1]),
                             fmaxf(s[1][qh][2], s[1][qh][3]));
      const float m2 = fmaxf(fmaxf(s[2][qh][0], s[2][qh][1]),
                             fmaxf(s[2][qh][2], s[2][qh][3]));
      const float m3 = fmaxf(fmaxf(s[3][qh][0], s[3][qh][1]),
                             fmaxf(s[3][qh][2], s[3][qh][3]));
      pml[qh] = fmaxf(fmaxf(m0, m1), fmaxf(m2, m3));
    }
    const bool need =
        __any((pml[0] > mrow[0] + THR) || (pml[1] > mrow[1] + THR));
    if (need) {
#pragma unroll
      for (int qh = 0; qh < 2; ++qh) {
        float p = pml[qh];
        p = fmaxf(p, __shfl_xor(p, 16));
        p = fmaxf(p, __shfl_xor(p, 32));
        const float mnew = fmaxf(mrow[qh], p);
        const float scl = exp2f(mrow[qh] - mnew);
        mrow[qh] = mnew;
        accl[qh][0] *= scl; accl[qh][1] *= scl;
        accl[qh][2] *= scl; accl[qh][3] *= scl;
#pragma unroll
        for (int dt = 0; dt < 8; ++dt) {
          acc[dt][qh][0] *= scl; acc[dt][qh][1] *= scl;
          acc[dt][qh][2] *= scl; acc[dt][qh][3] *= scl;
        }
      }
    }
#pragma unroll
    for (int qh = 0; qh < 2; ++qh)
#pragma unroll
      for (int ct = 0; ct < 4; ++ct)
#pragma unroll
        for (int i = 0; i < 4; ++i)
          s[ct][qh][i] = exp2f(s[ct][qh][i] - mrow[qh]);

    u32 pfw[2][2][4];
#pragma unroll
    for (int kc = 0; kc < 2; ++kc) {
#pragma unroll
      for (int qh = 0; qh < 2; ++qh) {
        const u32 lo0 = cvt_pk_bf16(s[kc * 2][qh][0], s[kc * 2][qh][1]);
        const u32 lo1 = cvt_pk_bf16(s[kc * 2][qh][2], s[kc * 2][qh][3]);
        const u32 hi0 = cvt_pk_bf16(s[kc * 2 + 1][qh][0], s[kc * 2 + 1][qh][1]);
        const u32 hi1 = cvt_pk_bf16(s[kc * 2 + 1][qh][2], s[kc * 2 + 1][qh][3]);
        pfw[kc][qh][0] = ghi ? hi0 : lo0;
        pfw[kc][qh][1] = ghi ? hi1 : lo1;
        const u32 s0 = ghi ? lo0 : hi0;
        const u32 s1 = ghi ? lo1 : hi1;
        pfw[kc][qh][2] = (u32)__shfl_xor((int)s0, 32);
        pfw[kc][qh][3] = (u32)__shfl_xor((int)s1, 32);
      }
    }

#pragma unroll
    for (int kc = 0; kc < 2; ++kc) {
      union { u32 w2[4]; bf16x8 v; } u0, u1;
#pragma unroll
      for (int j = 0; j < 4; ++j) { u0.w2[j] = pfw[kc][0][j]; u1.w2[j] = pfw[kc][1][j]; }
      __builtin_amdgcn_s_setprio(1);
      accl[0] = __builtin_amdgcn_mfma_f32_16x16x32_bf16(onesv, u0.v, accl[0], 0, 0, 0);
      accl[1] = __builtin_amdgcn_mfma_f32_16x16x32_bf16(onesv, u1.v, accl[1], 0, 0, 0);
#pragma unroll
      for (int dt = 0; dt < 8; ++dt) {
        const bf16x8 vf = *(const bf16x8*)&vb[vIdx(dt * 16 + c, kc * 32 + g * 8)];
        acc[dt][0] = __builtin_amdgcn_mfma_f32_16x16x32_bf16(vf, u0.v, acc[dt][0], 0, 0, 0);
        acc[dt][1] = __builtin_amdgcn_mfma_f32_16x16x32_bf16(vf, u1.v, acc[dt][1], 0, 0, 0);
      }
      __builtin_amdgcn_s_setprio(0);
    }
  };

  for (int kt = 0; kt < NT; kt += 2) {
    __syncthreads();
#pragma unroll
    for (int h = 0; h < 2; ++h)
#pragma unroll
      for (int i = 0; i < 4; ++i) {
        const int idx = i * 256 + t;
        *(bf16x8*)&lds_k[h][kIdx(idx >> 4, (idx & 15) * 8)] = krg[h * 4 + i];
        const int d = idx >> 3, rc = idx & 7;
        const bf16x8 vv = vrg[h * 4 + i];
        s16x4 lo, hi;
        lo[0] = vv[0]; lo[1] = vv[1]; lo[2] = vv[2]; lo[3] = vv[3];
        hi[0] = vv[4]; hi[1] = vv[5]; hi[2] = vv[6]; hi[3] = vv[7];
        *(s16x4*)&lds_vt[h][vIdx(d, kprm(rc * 2))] = lo;
        *(s16x4*)&lds_vt[h][vIdx(d, kprm(rc * 2 + 1))] = hi;
      }
    if (kt + 2 < NT) load_pair(k0 + (kt + 2) * 64);
    __syncthreads();

    proc(&lds_k[0][0], &lds_vt[0][0]);
    proc(&lds_k[1][0], &lds_vt[1][0]);
  }

#pragma unroll
  for (int qh = 0; qh < 2; ++qh) {
    const int n = qw + qh * 16 + c;
    const float lr = accl[qh][0];
    if (mb) {
      u16* __restrict__ ob = op + ((size_t)(sid * B_ + b) * D_) * N_;
#pragma unroll
      for (int dt = 0; dt < 8; ++dt)
#pragma unroll
        for (int i = 0; i < 4; ++i)
          ob[(size_t)(dt * 16 + g * 4 + i) * N_ + n] = f2bf(acc[dt][qh][i]);
      if (g == 0) {
        mb[(size_t)(sid * B_ + b) * N_ + n] = mrow[qh];
        lb[(size_t)(sid * B_ + b) * N_ + n] = lr;
      }
    } else {
      const float linv = 1.0f / lr;
      float* __restrict__ ob = outf + (size_t)b * D_ * N_;
#pragma unroll
      for (int dt = 0; dt < 8; ++dt)
#pragma unroll
        for (int i = 0; i < 4; ++i)
          ob[(size_t)(dt * 16 + g * 4 + i) * N_ + n] = acc[dt][qh][i] * linv;
    }
  }
}

// -------- combine split-K partials (bf16, log2-domain stats) -> out ---------
__global__ __launch_bounds__(256) void combine_kernel(
    const u16* __restrict__ op, const float* __restrict__ mbu,
    const float* __restrict__ lbu, float* __restrict__ out, int S) {
  const int idx = blockIdx.x * 256 + threadIdx.x;  // over B*D*(N/4)
  const int n0 = (idx & (N_ / 4 - 1)) * 4;
  const int bd = idx >> 10;
  const int b = bd >> 7, d = bd & (D_ - 1);

  float4 msv[8], lsv[8];
  float M0 = -3e38f, M1 = -3e38f, M2 = -3e38f, M3 = -3e38f;
#pragma unroll
  for (int s = 0; s < 8; ++s)
    if (s < S) {
      msv[s] = *(const float4*)&mbu[(size_t)(s * B_ + b) * N_ + n0];
      lsv[s] = *(const float4*)&lbu[(size_t)(s * B_ + b) * N_ + n0];
      M0 = fmaxf(M0, msv[s].x); M1 = fmaxf(M1, msv[s].y);
      M2 = fmaxf(M2, msv[s].z); M3 = fmaxf(M3, msv[s].w);
    }
  float d0 = 0.f, d1 = 0.f, d2 = 0.f, d3 = 0.f;
  float a0 = 0.f, a1 = 0.f, a2 = 0.f, a3 = 0.f;
#pragma unroll
  for (int s = 0; s < 8; ++s)
    if (s < S) {
      const float w0 = exp2f(msv[s].x - M0);
      const float w1 = exp2f(msv[s].y - M1);
      const float w2 = exp2f(msv[s].z - M2);
      const float w3 = exp2f(msv[s].w - M3);
      d0 += lsv[s].x * w0; d1 += lsv[s].y * w1;
      d2 += lsv[s].z * w2; d3 += lsv[s].w * w3;
      const s16x4 o =
          *(const s16x4*)&op[((size_t)(s * B_ + b) * D_ + d) * N_ + n0];
      a0 += w0 * bf2f((u16)o[0]); a1 += w1 * bf2f((u16)o[1]);
      a2 += w2 * bf2f((u16)o[2]); a3 += w3 * bf2f((u16)o[3]);
    }
  float4 r = {a0 / d0, a1 / d1, a2 / d2, a3 / d3};
  *(float4*)&out[((size_t)b * D_ + d) * N_ + n0] = r;
}

extern "C" void kernel_launch(void* const* d_in, const int* in_sizes, int n_in,
                              void* d_out, int out_size, void* d_ws, size_t ws_size,
                              hipStream_t stream) {
  const float* x  = (const float*)d_in[0];
  const float* Wq = (const float*)d_in[1];
  const float* Wk = (const float*)d_in[2];
  const float* Wv = (const float*)d_in[3];
  float* out = (float*)d_out;

  u16* whi  = (u16*)d_ws;                      // [3][128][256] bf16 hi
  u16* wlo  = whi + (size_t)3 * 128 * 256;     // [3][128][256] bf16 lo
  u16* q_ws = wlo + (size_t)3 * 128 * 256;     // [B][N][D] bf16
  u16* k_ws = q_ws + (size_t)B_ * N_ * D_;     // [B][N][D] bf16
  u16* v_ws = k_ws + (size_t)B_ * N_ * D_;     // [B][D][N] bf16

  castw_kernel<<<96, 256, 0, stream>>>(Wq, Wk, Wv, whi, wlo);
  proj_kernel<<<dim3(N_ / 32, B_), 256, 0, stream>>>(x, whi, wlo, q_ws, k_ws,
                                                     v_ws);

  const size_t baseB =
      ((size_t)6 * 128 * 256 + (size_t)3 * B_ * N_ * D_) * 2;
  // S=4 -> 512 blocks = exactly 2 blocks/CU, NT=16 (even), bijective swizzle
  int S = 0;
  const int cands[3] = {4, 2, 1};
  for (int ci = 0; ci < 3; ++ci) {
    const int cand = cands[ci];
    const size_t need = baseB + (size_t)cand * ((size_t)B_ * D_ * N_ * 2 +
                                                (size_t)2 * B_ * N_ * 4);
    if (ws_size >= need) { S = cand; break; }
  }
  if (S > 1) {
    u16* opb = (u16*)((char*)d_ws + baseB);
    float* mbuf = (float*)(opb + (size_t)S * B_ * D_ * N_);
    float* lbuf = mbuf + (size_t)S * B_ * N_;
    attn_kernel<<<dim3(32 * B_ * S), 256, 0, stream>>>(
        q_ws, k_ws, v_ws, opb, mbuf, lbuf, nullptr, 64 / S, 64 % S, S);
    combine_kernel<<<(B_ * D_ * N_ / 4) / 256, 256, 0, stream>>>(opb, mbuf,
                                                                 lbuf, out, S);
  } else {
    attn_kernel<<<dim3(32 * B_), 256, 0, stream>>>(
        q_ws, k_ws, v_ws, nullptr, nullptr, nullptr, out, 64, 0, 1);
  }
}

// Round 21
// 95.783 us; speedup vs baseline: 1.0152x; 1.0152x over previous
//
#include <hip/hip_runtime.h>
#include <hip/hip_bf16.h>

#define B_ 4
#define C_ 256
#define D_ 128
#define N_ 4096

typedef float f32x4 __attribute__((ext_vector_type(4)));
typedef short bf16x8 __attribute__((ext_vector_type(8)));
typedef short s16x4 __attribute__((ext_vector_type(4)));
typedef unsigned short u16;
typedef unsigned int u32;

__device__ __forceinline__ u16 f2bf(float f) {
  unsigned u = __float_as_uint(f);
  u += 0x7fffu + ((u >> 16) & 1u);
  return (u16)(u >> 16);
}
__device__ __forceinline__ float bf2f(u16 v) {
  return __uint_as_float(((u32)v) << 16);
}
// HW packed f32->bf16 (RNE): a -> low half, b -> high half (validated r8)
__device__ __forceinline__ u32 cvt_pk_bf16(float a, float b) {
  u32 r;
  asm("v_cvt_pk_bf16_f32 %0, %1, %2" : "=v"(r) : "v"(a), "v"(b));
  return r;
}

// ------ W cast: f32 -> hi/lo bf16 pair [3][128][256]; Wq pre-scaled by log2e
__global__ __launch_bounds__(256) void castw_kernel(
    const float* __restrict__ Wq, const float* __restrict__ Wk,
    const float* __restrict__ Wv, u16* __restrict__ Whi,
    u16* __restrict__ Wlo) {
  const int i = blockIdx.x * 256 + threadIdx.x;  // 24576 threads x 4 elems
  const int m = i >> 13;
  const int j = (i & 8191) * 4;
  const float* src = (m == 0) ? Wq : (m == 1) ? Wk : Wv;
  const float scale = (m == 0) ? 1.44269504f : 1.0f;  // fold log2(e) into Q
  const float4 v = *(const float4*)(src + j);
  const float vv[4] = {v.x * scale, v.y * scale, v.z * scale, v.w * scale};
  s16x4 h, l;
#pragma unroll
  for (int k = 0; k < 4; ++k) {
    const u16 hb = f2bf(vv[k]);
    h[k] = (short)hb;
    l[k] = (short)f2bf(vv[k] - bf2f(hb));
  }
  *(s16x4*)&Whi[m * 32768 + j] = h;
  *(s16x4*)&Wlo[m * 32768 + j] = l;
}

// ------- projection via 3-term hi/lo MFMA: Q/K -> [N][D], V -> [D][N] -------
// 4 independent accumulator chains (2 dt x 2 nt); per-acc accumulation order
// identical to r17/r19 (bit-identical outputs).
__global__ __launch_bounds__(256, 2) void proj_kernel(
    const float* __restrict__ x, const u16* __restrict__ Whi,
    const u16* __restrict__ Wlo, u16* __restrict__ Qo, u16* __restrict__ Ko,
    u16* __restrict__ Vt) {
  __shared__ __align__(16) u16 xs_h[32 * 256];  // x^T hi [n][c], swizzled
  __shared__ __align__(16) u16 xs_l[32 * 256];  // x^T lo

  const int n0 = blockIdx.x * 32;
  const int b = blockIdx.y;
  const int t = threadIdx.x;
  const int w = t >> 6, lane = t & 63, g = lane >> 4, c = lane & 15;

  {
    const float* xb = x + ((size_t)b * C_) * N_ + n0;
#pragma unroll
    for (int r = 0; r < 8; ++r) {
      const int id = r * 256 + t;
      const int cr = id >> 3, nq = (id & 7) * 4;
      const float4 v = *(const float4*)(xb + (size_t)cr * N_ + nq);
      const u32 h01 = cvt_pk_bf16(v.x, v.y);
      const u32 h23 = cvt_pk_bf16(v.z, v.w);
      const float r0 = v.x - bf2f((u16)(h01 & 0xffffu));
      const float r1 = v.y - bf2f((u16)(h01 >> 16));
      const float r2 = v.z - bf2f((u16)(h23 & 0xffffu));
      const float r3 = v.w - bf2f((u16)(h23 >> 16));
      const u32 l01 = cvt_pk_bf16(r0, r1);
      const u32 l23 = cvt_pk_bf16(r2, r3);
      const u16 hv[4] = {(u16)(h01 & 0xffffu), (u16)(h01 >> 16),
                         (u16)(h23 & 0xffffu), (u16)(h23 >> 16)};
      const u16 lv[4] = {(u16)(l01 & 0xffffu), (u16)(l01 >> 16),
                         (u16)(l23 & 0xffffu), (u16)(l23 >> 16)};
#pragma unroll
      for (int k2 = 0; k2 < 4; ++k2) {
        const int idx2 = (nq + k2) * 256 + (cr ^ (((nq + k2) & 7) << 3));
        xs_h[idx2] = hv[k2];
        xs_l[idx2] = lv[k2];
      }
    }
  }
  __syncthreads();

  if (w < 2) {
    // Q (w=0) / K (w=1): 8 dt tiles, processed in pairs with 4 acc chains
    const size_t wo = (size_t)w * 32768;
    u16* __restrict__ O = (w == 0 ? Qo : Ko) + (size_t)b * N_ * D_;
#pragma unroll 1
    for (int dtg = 0; dtg < 4; ++dtg) {
      f32x4 a00 = {0.f, 0.f, 0.f, 0.f};  // [dt0][nt0]
      f32x4 a01 = {0.f, 0.f, 0.f, 0.f};  // [dt0][nt1]
      f32x4 a10 = {0.f, 0.f, 0.f, 0.f};  // [dt1][nt0]
      f32x4 a11 = {0.f, 0.f, 0.f, 0.f};  // [dt1][nt1]
      const int dt0 = dtg * 2, dt1 = dtg * 2 + 1;
#pragma unroll 1
      for (int kcb = 0; kcb < 2; ++kcb) {
        bf16x8 w0h[4], w0l[4], w1h[4], w1l[4];
#pragma unroll
        for (int j = 0; j < 4; ++j) {
          const size_t o0 = wo + (size_t)(dt0 * 16 + c) * 256 +
                            (kcb * 4 + j) * 32 + g * 8;
          const size_t o1 = wo + (size_t)(dt1 * 16 + c) * 256 +
                            (kcb * 4 + j) * 32 + g * 8;
          w0h[j] = *(const bf16x8*)&Whi[o0];
          w0l[j] = *(const bf16x8*)&Wlo[o0];
          w1h[j] = *(const bf16x8*)&Whi[o1];
          w1l[j] = *(const bf16x8*)&Wlo[o1];
        }
#pragma unroll
        for (int j = 0; j < 4; ++j) {
          const int kc = kcb * 4 + j;
          const int col = (kc * 32 + g * 8) ^ ((c & 7) << 3);
          const bf16x8 xh0 = *(const bf16x8*)&xs_h[c * 256 + col];
          const bf16x8 xl0 = *(const bf16x8*)&xs_l[c * 256 + col];
          const bf16x8 xh1 = *(const bf16x8*)&xs_h[(16 + c) * 256 + col];
          const bf16x8 xl1 = *(const bf16x8*)&xs_l[(16 + c) * 256 + col];
          a00 = __builtin_amdgcn_mfma_f32_16x16x32_bf16(xh0, w0h[j], a00, 0, 0, 0);
          a01 = __builtin_amdgcn_mfma_f32_16x16x32_bf16(xh1, w0h[j], a01, 0, 0, 0);
          a10 = __builtin_amdgcn_mfma_f32_16x16x32_bf16(xh0, w1h[j], a10, 0, 0, 0);
          a11 = __builtin_amdgcn_mfma_f32_16x16x32_bf16(xh1, w1h[j], a11, 0, 0, 0);
          a00 = __builtin_amdgcn_mfma_f32_16x16x32_bf16(xh0, w0l[j], a00, 0, 0, 0);
          a01 = __builtin_amdgcn_mfma_f32_16x16x32_bf16(xh1, w0l[j], a01, 0, 0, 0);
          a10 = __builtin_amdgcn_mfma_f32_16x16x32_bf16(xh0, w1l[j], a10, 0, 0, 0);
          a11 = __builtin_amdgcn_mfma_f32_16x16x32_bf16(xh1, w1l[j], a11, 0, 0, 0);
          a00 = __builtin_amdgcn_mfma_f32_16x16x32_bf16(xl0, w0h[j], a00, 0, 0, 0);
          a01 = __builtin_amdgcn_mfma_f32_16x16x32_bf16(xl1, w0h[j], a01, 0, 0, 0);
          a10 = __builtin_amdgcn_mfma_f32_16x16x32_bf16(xl0, w1h[j], a10, 0, 0, 0);
          a11 = __builtin_amdgcn_mfma_f32_16x16x32_bf16(xl1, w1h[j], a11, 0, 0, 0);
        }
      }
#pragma unroll
      for (int i = 0; i < 4; ++i) {
        O[(size_t)(n0 + g * 4 + i) * D_ + dt0 * 16 + c] = f2bf(a00[i]);
        O[(size_t)(n0 + 16 + g * 4 + i) * D_ + dt0 * 16 + c] = f2bf(a01[i]);
        O[(size_t)(n0 + g * 4 + i) * D_ + dt1 * 16 + c] = f2bf(a10[i]);
        O[(size_t)(n0 + 16 + g * 4 + i) * D_ + dt1 * 16 + c] = f2bf(a11[i]);
      }
    }
  } else {
    // V (w=2,3): 4 dt tiles each, processed in pairs with 4 acc chains
    const size_t wo = (size_t)2 * 32768;
    const int dbase = (w - 2) * 64;
    u16* __restrict__ O = Vt + (size_t)b * D_ * N_;
#pragma unroll 1
    for (int dtg = 0; dtg < 2; ++dtg) {
      f32x4 a00 = {0.f, 0.f, 0.f, 0.f};
      f32x4 a01 = {0.f, 0.f, 0.f, 0.f};
      f32x4 a10 = {0.f, 0.f, 0.f, 0.f};
      f32x4 a11 = {0.f, 0.f, 0.f, 0.f};
      const int dr0 = dbase + dtg * 32, dr1 = dbase + dtg * 32 + 16;
#pragma unroll 1
      for (int kcb = 0; kcb < 2; ++kcb) {
        bf16x8 w0h[4], w0l[4], w1h[4], w1l[4];
#pragma unroll
        for (int j = 0; j < 4; ++j) {
          const size_t o0 =
              wo + (size_t)(dr0 + c) * 256 + (kcb * 4 + j) * 32 + g * 8;
          const size_t o1 =
              wo + (size_t)(dr1 + c) * 256 + (kcb * 4 + j) * 32 + g * 8;
          w0h[j] = *(const bf16x8*)&Whi[o0];
          w0l[j] = *(const bf16x8*)&Wlo[o0];
          w1h[j] = *(const bf16x8*)&Whi[o1];
          w1l[j] = *(const bf16x8*)&Wlo[o1];
        }
#pragma unroll
        for (int j = 0; j < 4; ++j) {
          const int kc = kcb * 4 + j;
          const int col = (kc * 32 + g * 8) ^ ((c & 7) << 3);
          const bf16x8 xh0 = *(const bf16x8*)&xs_h[c * 256 + col];
          const bf16x8 xl0 = *(const bf16x8*)&xs_l[c * 256 + col];
          const bf16x8 xh1 = *(const bf16x8*)&xs_h[(16 + c) * 256 + col];
          const bf16x8 xl1 = *(const bf16x8*)&xs_l[(16 + c) * 256 + col];
          a00 = __builtin_amdgcn_mfma_f32_16x16x32_bf16(w0h[j], xh0, a00, 0, 0, 0);
          a01 = __builtin_amdgcn_mfma_f32_16x16x32_bf16(w0h[j], xh1, a01, 0, 0, 0);
          a10 = __builtin_amdgcn_mfma_f32_16x16x32_bf16(w1h[j], xh0, a10, 0, 0, 0);
          a11 = __builtin_amdgcn_mfma_f32_16x16x32_bf16(w1h[j], xh1, a11, 0, 0, 0);
          a00 = __builtin_amdgcn_mfma_f32_16x16x32_bf16(w0l[j], xh0, a00, 0, 0, 0);
          a01 = __builtin_amdgcn_mfma_f32_16x16x32_bf16(w0l[j], xh1, a01, 0, 0, 0);
          a10 = __builtin_amdgcn_mfma_f32_16x16x32_bf16(w1l[j], xh0, a10, 0, 0, 0);
          a11 = __builtin_amdgcn_mfma_f32_16x16x32_bf16(w1l[j], xh1, a11, 0, 0, 0);
          a00 = __builtin_amdgcn_mfma_f32_16x16x32_bf16(w0h[j], xl0, a00, 0, 0, 0);
          a01 = __builtin_amdgcn_mfma_f32_16x16x32_bf16(w0h[j], xl1, a01, 0, 0, 0);
          a10 = __builtin_amdgcn_mfma_f32_16x16x32_bf16(w1h[j], xl0, a10, 0, 0, 0);
          a11 = __builtin_amdgcn_mfma_f32_16x16x32_bf16(w1h[j], xl1, a11, 0, 0, 0);
        }
      }
#pragma unroll
      for (int i = 0; i < 4; ++i) {
        O[(size_t)(dr0 + g * 4 + i) * N_ + n0 + c] = f2bf(a00[i]);
        O[(size_t)(dr0 + g * 4 + i) * N_ + n0 + 16 + c] = f2bf(a01[i]);
        O[(size_t)(dr1 + g * 4 + i) * N_ + n0 + c] = f2bf(a10[i]);
        O[(size_t)(dr1 + g * 4 + i) * N_ + n0 + 16 + c] = f2bf(a11[i]);
      }
    }
  }
}

// swizzled LDS index helpers (u16 units)
__device__ __forceinline__ int kIdx(int row, int col) {
  return row * 128 + (col ^ ((row & 7) << 3));
}
__device__ __forceinline__ int vIdx(int d, int col) {
  return d * 64 + (col ^ ((d & 7) << 3));
}
// V k-column permutation (validated end-to-end in rounds 6/12-20)
__device__ __forceinline__ int kprm(int q) {
  const int ct = q >> 2, qq = q & 3;
  return ((ct >> 1) << 5) +
         (((qq >> 1) == (ct & 1)) ? (qq << 3) : (((qq ^ 2) << 3) + 4));
}

// -------- flash attention (split-K), 32 q-rows/wave, KVBLK=128 pairs --------
// r17 body + wave-parity slot stagger: waves 0-1 process slot0->slot1, waves
// 2-3 slot1->slot0 (slots read-only after barrier; online softmax order is
// commutative). Halves same-slot LDS read pressure; desyncs wave phases.
__global__ __launch_bounds__(256, 2) void attn_kernel(
    const u16* __restrict__ Q, const u16* __restrict__ K,
    const u16* __restrict__ Vt, u16* __restrict__ op,
    float* __restrict__ mb, float* __restrict__ lb,
    float* __restrict__ outf, int qt, int rem, int S) {
  __shared__ __align__(16) u16 lds_k[2][64 * 128];   // [slot][kpos][d]
  __shared__ __align__(16) u16 lds_vt[2][128 * 64];  // [slot][d][k']

  const int L = blockIdx.x;
  int qx, b, sid;
  if (((B_ * S) & 7) == 0) {
    const int gpx = (B_ * S) >> 3;
    const int xcd = L & 7, idx = L >> 3;
    const int grp = xcd * gpx + (idx >> 5);
    qx = idx & 31;
    b = grp / S;
    sid = grp - b * S;
  } else {
    qx = L & 31;
    const int r2 = L >> 5;
    b = r2 % B_;
    sid = r2 / B_;
  }
  const int q0 = qx * 128;
  const int NT = qt + (sid < rem ? 1 : 0);  // S in {4,2,1}: NT always even
  const int t0 = sid * qt + (sid < rem ? sid : rem);
  const int k0 = t0 * 64;
  const int t = threadIdx.x;
  const int w = t >> 6, lane = t & 63, g = lane >> 4, c = lane & 15;
  const int qw = q0 + w * 32;
  const bool ghi = (g & 2) != 0;

  const u16* __restrict__ Qb = Q + (size_t)b * N_ * D_;
  const u16* __restrict__ Kb = K + (size_t)b * N_ * D_;
  const u16* __restrict__ Vb = Vt + (size_t)b * D_ * N_;

  bf16x8 qf[2][4];
#pragma unroll
  for (int qh = 0; qh < 2; ++qh)
#pragma unroll
    for (int kc = 0; kc < 4; ++kc)
      qf[qh][kc] =
          *(const bf16x8*)&Qb[(size_t)(qw + qh * 16 + c) * D_ + kc * 32 + g * 8];

  f32x4 acc[8][2];
  f32x4 accl[2];
#pragma unroll
  for (int dt = 0; dt < 8; ++dt)
#pragma unroll
    for (int qh = 0; qh < 2; ++qh) acc[dt][qh] = (f32x4){0.f, 0.f, 0.f, 0.f};
  accl[0] = (f32x4){0.f, 0.f, 0.f, 0.f};
  accl[1] = (f32x4){0.f, 0.f, 0.f, 0.f};
  float mrow[2] = {-3.0e38f, -3.0e38f};
  const float THR = 11.5415603f;  // 8 * log2(e)

  bf16x8 onesv;
#pragma unroll
  for (int j = 0; j < 8; ++j) onesv[j] = (short)0x3F80;

  bf16x8 krg[8], vrg[8];
  auto load_pair = [&](int kbase) {
#pragma unroll
    for (int h = 0; h < 2; ++h)
#pragma unroll
      for (int i = 0; i < 4; ++i) {
        const int idx = i * 256 + t;
        const int kb2 = kbase + h * 64;
        krg[h * 4 + i] =
            *(const bf16x8*)&Kb[(size_t)(kb2 + (idx >> 4)) * D_ + (idx & 15) * 8];
        vrg[h * 4 + i] =
            *(const bf16x8*)&Vb[(size_t)(idx >> 3) * N_ + kb2 + (idx & 7) * 8];
      }
  };
  load_pair(k0);

  auto proc = [&](const u16* kb, const u16* vb) {
    f32x4 s[4][2];
#pragma unroll
    for (int ct = 0; ct < 4; ++ct)
#pragma unroll
      for (int qh = 0; qh < 2; ++qh) s[ct][qh] = (f32x4){0.f, 0.f, 0.f, 0.f};
    __builtin_amdgcn_s_setprio(1);
#pragma unroll
    for (int kc = 0; kc < 4; ++kc) {
#pragma unroll
      for (int ct = 0; ct < 4; ++ct) {
        const bf16x8 kf = *(const bf16x8*)&kb[kIdx(ct * 16 + c, kc * 32 + g * 8)];
        s[ct][0] = __builtin_amdgcn_mfma_f32_16x16x32_bf16(kf, qf[0][kc], s[ct][0], 0, 0, 0);
        s[ct][1] = __builtin_amdgcn_mfma_f32_16x16x32_bf16(kf, qf[1][kc], s[ct][1], 0, 0, 0);
      }
    }
    __builtin_amdgcn_s_setprio(0);

    float pml[2];
#pragma unroll
    for (int qh = 0; qh < 2; ++qh) {
      const float m0 = fmaxf(fmaxf(s[0][qh][0], s[0][qh][1]),
                             fmaxf(s[0][qh][2], s[0][qh][3]));
      const float m1 = fmaxf(fmaxf(s[1][qh][0], s[1][qh][1]),
                             fmaxf(s[1][qh][2], s[1][qh][3]));
      const float m2 = fmaxf(fmaxf(s[2][qh][0], s[2][qh][1]),
                             fmaxf(s[2][qh][2], s[2][qh][3]));
      const float m3 = fmaxf(fmaxf(s[3][qh][0], s[3][qh][1]),
                             fmaxf(s[3][qh][2], s[3][qh][3]));
      pml[qh] = fmaxf(fmaxf(m0, m1), fmaxf(m2, m3));
    }
    const bool need =
        __any((pml[0] > mrow[0] + THR) || (pml[1] > mrow[1] + THR));
    if (need) {
#pragma unroll
      for (int qh = 0; qh < 2; ++qh) {
        float p = pml[qh];
        p = fmaxf(p, __shfl_xor(p, 16));
        p = fmaxf(p, __shfl_xor(p, 32));
        const float mnew = fmaxf(mrow[qh], p);
        const float scl = exp2f(mrow[qh] - mnew);
        mrow[qh] = mnew;
        accl[qh][0] *= scl; accl[qh][1] *= scl;
        accl[qh][2] *= scl; accl[qh][3] *= scl;
#pragma unroll
        for (int dt = 0; dt < 8; ++dt) {
          acc[dt][qh][0] *= scl; acc[dt][qh][1] *= scl;
          acc[dt][qh][2] *= scl; acc[dt][qh][3] *= scl;
        }
      }
    }
#pragma unroll
    for (int qh = 0; qh < 2; ++qh)
#pragma unroll
      for (int ct = 0; ct < 4; ++ct)
#pragma unroll
        for (int i = 0; i < 4; ++i)
          s[ct][qh][i] = exp2f(s[ct][qh][i] - mrow[qh]);

    u32 pfw[2][2][4];
#pragma unroll
    for (int kc = 0; kc < 2; ++kc) {
#pragma unroll
      for (int qh = 0; qh < 2; ++qh) {
        const u32 lo0 = cvt_pk_bf16(s[kc * 2][qh][0], s[kc * 2][qh][1]);
        const u32 lo1 = cvt_pk_bf16(s[kc * 2][qh][2], s[kc * 2][qh][3]);
        const u32 hi0 = cvt_pk_bf16(s[kc * 2 + 1][qh][0], s[kc * 2 + 1][qh][1]);
        const u32 hi1 = cvt_pk_bf16(s[kc * 2 + 1][qh][2], s[kc * 2 + 1][qh][3]);
        pfw[kc][qh][0] = ghi ? hi0 : lo0;
        pfw[kc][qh][1] = ghi ? hi1 : lo1;
        const u32 s0 = ghi ? lo0 : hi0;
        const u32 s1 = ghi ? lo1 : hi1;
        pfw[kc][qh][2] = (u32)__shfl_xor((int)s0, 32);
        pfw[kc][qh][3] = (u32)__shfl_xor((int)s1, 32);
      }
    }

#pragma unroll
    for (int kc = 0; kc < 2; ++kc) {
      union { u32 w2[4]; bf16x8 v; } u0, u1;
#pragma unroll
      for (int j = 0; j < 4; ++j) { u0.w2[j] = pfw[kc][0][j]; u1.w2[j] = pfw[kc][1][j]; }
      __builtin_amdgcn_s_setprio(1);
      accl[0] = __builtin_amdgcn_mfma_f32_16x16x32_bf16(onesv, u0.v, accl[0], 0, 0, 0);
      accl[1] = __builtin_amdgcn_mfma_f32_16x16x32_bf16(onesv, u1.v, accl[1], 0, 0, 0);
#pragma unroll
      for (int dt = 0; dt < 8; ++dt) {
        const bf16x8 vf = *(const bf16x8*)&vb[vIdx(dt * 16 + c, kc * 32 + g * 8)];
        acc[dt][0] = __builtin_amdgcn_mfma_f32_16x16x32_bf16(vf, u0.v, acc[dt][0], 0, 0, 0);
        acc[dt][1] = __builtin_amdgcn_mfma_f32_16x16x32_bf16(vf, u1.v, acc[dt][1], 0, 0, 0);
      }
      __builtin_amdgcn_s_setprio(0);
    }
  };

  for (int kt = 0; kt < NT; kt += 2) {
    __syncthreads();
#pragma unroll
    for (int h = 0; h < 2; ++h)
#pragma unroll
      for (int i = 0; i < 4; ++i) {
        const int idx = i * 256 + t;
        *(bf16x8*)&lds_k[h][kIdx(idx >> 4, (idx & 15) * 8)] = krg[h * 4 + i];
        const int d = idx >> 3, rc = idx & 7;
        const bf16x8 vv = vrg[h * 4 + i];
        s16x4 lo, hi;
        lo[0] = vv[0]; lo[1] = vv[1]; lo[2] = vv[2]; lo[3] = vv[3];
        hi[0] = vv[4]; hi[1] = vv[5]; hi[2] = vv[6]; hi[3] = vv[7];
        *(s16x4*)&lds_vt[h][vIdx(d, kprm(rc * 2))] = lo;
        *(s16x4*)&lds_vt[h][vIdx(d, kprm(rc * 2 + 1))] = hi;
      }
    if (kt + 2 < NT) load_pair(k0 + (kt + 2) * 64);
    __syncthreads();

    // wave-parity slot stagger (slots read-only here; order commutes)
    if (w < 2) {
      proc(&lds_k[0][0], &lds_vt[0][0]);
      proc(&lds_k[1][0], &lds_vt[1][0]);
    } else {
      proc(&lds_k[1][0], &lds_vt[1][0]);
      proc(&lds_k[0][0], &lds_vt[0][0]);
    }
  }

#pragma unroll
  for (int qh = 0; qh < 2; ++qh) {
    const int n = qw + qh * 16 + c;
    const float lr = accl[qh][0];
    if (mb) {
      u16* __restrict__ ob = op + ((size_t)(sid * B_ + b) * D_) * N_;
#pragma unroll
      for (int dt = 0; dt < 8; ++dt)
#pragma unroll
        for (int i = 0; i < 4; ++i)
          ob[(size_t)(dt * 16 + g * 4 + i) * N_ + n] = f2bf(acc[dt][qh][i]);
      if (g == 0) {
        mb[(size_t)(sid * B_ + b) * N_ + n] = mrow[qh];
        lb[(size_t)(sid * B_ + b) * N_ + n] = lr;
      }
    } else {
      const float linv = 1.0f / lr;
      float* __restrict__ ob = outf + (size_t)b * D_ * N_;
#pragma unroll
      for (int dt = 0; dt < 8; ++dt)
#pragma unroll
        for (int i = 0; i < 4; ++i)
          ob[(size_t)(dt * 16 + g * 4 + i) * N_ + n] = acc[dt][qh][i] * linv;
    }
  }
}

// -------- combine split-K partials (bf16, log2-domain stats) -> out ---------
__global__ __launch_bounds__(256) void combine_kernel(
    const u16* __restrict__ op, const float* __restrict__ mbu,
    const float* __restrict__ lbu, float* __restrict__ out, int S) {
  const int idx = blockIdx.x * 256 + threadIdx.x;  // over B*D*(N/4)
  const int n0 = (idx & (N_ / 4 - 1)) * 4;
  const int bd = idx >> 10;
  const int b = bd >> 7, d = bd & (D_ - 1);

  float4 msv[8], lsv[8];
  float M0 = -3e38f, M1 = -3e38f, M2 = -3e38f, M3 = -3e38f;
#pragma unroll
  for (int s = 0; s < 8; ++s)
    if (s < S) {
      msv[s] = *(const float4*)&mbu[(size_t)(s * B_ + b) * N_ + n0];
      lsv[s] = *(const float4*)&lbu[(size_t)(s * B_ + b) * N_ + n0];
      M0 = fmaxf(M0, msv[s].x); M1 = fmaxf(M1, msv[s].y);
      M2 = fmaxf(M2, msv[s].z); M3 = fmaxf(M3, msv[s].w);
    }
  float d0 = 0.f, d1 = 0.f, d2 = 0.f, d3 = 0.f;
  float a0 = 0.f, a1 = 0.f, a2 = 0.f, a3 = 0.f;
#pragma unroll
  for (int s = 0; s < 8; ++s)
    if (s < S) {
      const float w0 = exp2f(msv[s].x - M0);
      const float w1 = exp2f(msv[s].y - M1);
      const float w2 = exp2f(msv[s].z - M2);
      const float w3 = exp2f(msv[s].w - M3);
      d0 += lsv[s].x * w0; d1 += lsv[s].y * w1;
      d2 += lsv[s].z * w2; d3 += lsv[s].w * w3;
      const s16x4 o =
          *(const s16x4*)&op[((size_t)(s * B_ + b) * D_ + d) * N_ + n0];
      a0 += w0 * bf2f((u16)o[0]); a1 += w1 * bf2f((u16)o[1]);
      a2 += w2 * bf2f((u16)o[2]); a3 += w3 * bf2f((u16)o[3]);
    }
  float4 r = {a0 / d0, a1 / d1, a2 / d2, a3 / d3};
  *(float4*)&out[((size_t)b * D_ + d) * N_ + n0] = r;
}

extern "C" void kernel_launch(void* const* d_in, const int* in_sizes, int n_in,
                              void* d_out, int out_size, void* d_ws, size_t ws_size,
                              hipStream_t stream) {
  const float* x  = (const float*)d_in[0];
  const float* Wq = (const float*)d_in[1];
  const float* Wk = (const float*)d_in[2];
  const float* Wv = (const float*)d_in[3];
  float* out = (float*)d_out;

  u16* whi  = (u16*)d_ws;                      // [3][128][256] bf16 hi
  u16* wlo  = whi + (size_t)3 * 128 * 256;     // [3][128][256] bf16 lo
  u16* q_ws = wlo + (size_t)3 * 128 * 256;     // [B][N][D] bf16
  u16* k_ws = q_ws + (size_t)B_ * N_ * D_;     // [B][N][D] bf16
  u16* v_ws = k_ws + (size_t)B_ * N_ * D_;     // [B][D][N] bf16

  castw_kernel<<<96, 256, 0, stream>>>(Wq, Wk, Wv, whi, wlo);
  proj_kernel<<<dim3(N_ / 32, B_), 256, 0, stream>>>(x, whi, wlo, q_ws, k_ws,
                                                     v_ws);

  const size_t baseB =
      ((size_t)6 * 128 * 256 + (size_t)3 * B_ * N_ * D_) * 2;
  // S=4 -> 512 blocks = exactly 2 blocks/CU, NT=16 (even), bijective swizzle
  int S = 0;
  const int cands[3] = {4, 2, 1};
  for (int ci = 0; ci < 3; ++ci) {
    const int cand = cands[ci];
    const size_t need = baseB + (size_t)cand * ((size_t)B_ * D_ * N_ * 2 +
                                                (size_t)2 * B_ * N_ * 4);
    if (ws_size >= need) { S = cand; break; }
  }
  if (S > 1) {
    u16* opb = (u16*)((char*)d_ws + baseB);
    float* mbuf = (float*)(opb + (size_t)S * B_ * D_ * N_);
    float* lbuf = mbuf + (size_t)S * B_ * N_;
    attn_kernel<<<dim3(32 * B_ * S), 256, 0, stream>>>(
        q_ws, k_ws, v_ws, opb, mbuf, lbuf, nullptr, 64 / S, 64 % S, S);
    combine_kernel<<<(B_ * D_ * N_ / 4) / 256, 256, 0, stream>>>(opb, mbuf,
                                                                 lbuf, out, S);
  } else {
    attn_kernel<<<dim3(32 * B_), 256, 0, stream>>>(
        q_ws, k_ws, v_ws, nullptr, nullptr, nullptr, out, 64, 0, 1);
  }
}

// Round 22
// 95.647 us; speedup vs baseline: 1.0167x; 1.0014x over previous
//
#include <hip/hip_runtime.h>
#include <hip/hip_bf16.h>

#define B_ 4
#define C_ 256
#define D_ 128
#define N_ 4096

typedef float f32x4 __attribute__((ext_vector_type(4)));
typedef short bf16x8 __attribute__((ext_vector_type(8)));
typedef short s16x4 __attribute__((ext_vector_type(4)));
typedef unsigned short u16;
typedef unsigned int u32;

__device__ __forceinline__ u16 f2bf(float f) {
  unsigned u = __float_as_uint(f);
  u += 0x7fffu + ((u >> 16) & 1u);
  return (u16)(u >> 16);
}
__device__ __forceinline__ float bf2f(u16 v) {
  return __uint_as_float(((u32)v) << 16);
}
// HW packed f32->bf16 (RNE): a -> low half, b -> high half (validated r8)
__device__ __forceinline__ u32 cvt_pk_bf16(float a, float b) {
  u32 r;
  asm("v_cvt_pk_bf16_f32 %0, %1, %2" : "=v"(r) : "v"(a), "v"(b));
  return r;
}

// ------ W cast: f32 -> hi/lo bf16 pair [3][128][256]; Wq pre-scaled by log2e
__global__ __launch_bounds__(256) void castw_kernel(
    const float* __restrict__ Wq, const float* __restrict__ Wk,
    const float* __restrict__ Wv, u16* __restrict__ Whi,
    u16* __restrict__ Wlo) {
  const int i = blockIdx.x * 256 + threadIdx.x;  // 24576 threads x 4 elems
  const int m = i >> 13;
  const int j = (i & 8191) * 4;
  const float* src = (m == 0) ? Wq : (m == 1) ? Wk : Wv;
  const float scale = (m == 0) ? 1.44269504f : 1.0f;  // fold log2(e) into Q
  const float4 v = *(const float4*)(src + j);
  const float vv[4] = {v.x * scale, v.y * scale, v.z * scale, v.w * scale};
  s16x4 h, l;
#pragma unroll
  for (int k = 0; k < 4; ++k) {
    const u16 hb = f2bf(vv[k]);
    h[k] = (short)hb;
    l[k] = (short)f2bf(vv[k] - bf2f(hb));
  }
  *(s16x4*)&Whi[m * 32768 + j] = h;
  *(s16x4*)&Wlo[m * 32768 + j] = l;
}

// ------- projection via 3-term hi/lo MFMA: Q/K -> [N][D], V -> [D][N] -------
// 4 independent accumulator chains (2 dt x 2 nt); per-acc accumulation order
// identical to r17-r21 (bit-identical outputs). Role rotated per block so
// heavy (Q/K, 384 MFMA) and light (V, 192 MFMA) waves mix across SIMDs.
__global__ __launch_bounds__(256, 2) void proj_kernel(
    const float* __restrict__ x, const u16* __restrict__ Whi,
    const u16* __restrict__ Wlo, u16* __restrict__ Qo, u16* __restrict__ Ko,
    u16* __restrict__ Vt) {
  __shared__ __align__(16) u16 xs_h[32 * 256];  // x^T hi [n][c], swizzled
  __shared__ __align__(16) u16 xs_l[32 * 256];  // x^T lo

  const int n0 = blockIdx.x * 32;
  const int b = blockIdx.y;
  const int t = threadIdx.x;
  const int w = t >> 6, lane = t & 63, g = lane >> 4, c = lane & 15;
  const int role = (w + blockIdx.x) & 3;  // balance heavy/light across SIMDs

  {
    const float* xb = x + ((size_t)b * C_) * N_ + n0;
#pragma unroll
    for (int r = 0; r < 8; ++r) {
      const int id = r * 256 + t;
      const int cr = id >> 3, nq = (id & 7) * 4;
      const float4 v = *(const float4*)(xb + (size_t)cr * N_ + nq);
      const u32 h01 = cvt_pk_bf16(v.x, v.y);
      const u32 h23 = cvt_pk_bf16(v.z, v.w);
      const float r0 = v.x - bf2f((u16)(h01 & 0xffffu));
      const float r1 = v.y - bf2f((u16)(h01 >> 16));
      const float r2 = v.z - bf2f((u16)(h23 & 0xffffu));
      const float r3 = v.w - bf2f((u16)(h23 >> 16));
      const u32 l01 = cvt_pk_bf16(r0, r1);
      const u32 l23 = cvt_pk_bf16(r2, r3);
      const u16 hv[4] = {(u16)(h01 & 0xffffu), (u16)(h01 >> 16),
                         (u16)(h23 & 0xffffu), (u16)(h23 >> 16)};
      const u16 lv[4] = {(u16)(l01 & 0xffffu), (u16)(l01 >> 16),
                         (u16)(l23 & 0xffffu), (u16)(l23 >> 16)};
#pragma unroll
      for (int k2 = 0; k2 < 4; ++k2) {
        const int idx2 = (nq + k2) * 256 + (cr ^ (((nq + k2) & 7) << 3));
        xs_h[idx2] = hv[k2];
        xs_l[idx2] = lv[k2];
      }
    }
  }
  __syncthreads();

  if (role < 2) {
    // Q (role 0) / K (role 1): 8 dt tiles, processed in pairs, 4 acc chains
    const size_t wo = (size_t)role * 32768;
    u16* __restrict__ O = (role == 0 ? Qo : Ko) + (size_t)b * N_ * D_;
#pragma unroll 1
    for (int dtg = 0; dtg < 4; ++dtg) {
      f32x4 a00 = {0.f, 0.f, 0.f, 0.f};  // [dt0][nt0]
      f32x4 a01 = {0.f, 0.f, 0.f, 0.f};  // [dt0][nt1]
      f32x4 a10 = {0.f, 0.f, 0.f, 0.f};  // [dt1][nt0]
      f32x4 a11 = {0.f, 0.f, 0.f, 0.f};  // [dt1][nt1]
      const int dt0 = dtg * 2, dt1 = dtg * 2 + 1;
#pragma unroll 1
      for (int kcb = 0; kcb < 2; ++kcb) {
        bf16x8 w0h[4], w0l[4], w1h[4], w1l[4];
#pragma unroll
        for (int j = 0; j < 4; ++j) {
          const size_t o0 = wo + (size_t)(dt0 * 16 + c) * 256 +
                            (kcb * 4 + j) * 32 + g * 8;
          const size_t o1 = wo + (size_t)(dt1 * 16 + c) * 256 +
                            (kcb * 4 + j) * 32 + g * 8;
          w0h[j] = *(const bf16x8*)&Whi[o0];
          w0l[j] = *(const bf16x8*)&Wlo[o0];
          w1h[j] = *(const bf16x8*)&Whi[o1];
          w1l[j] = *(const bf16x8*)&Wlo[o1];
        }
#pragma unroll
        for (int j = 0; j < 4; ++j) {
          const int kc = kcb * 4 + j;
          const int col = (kc * 32 + g * 8) ^ ((c & 7) << 3);
          const bf16x8 xh0 = *(const bf16x8*)&xs_h[c * 256 + col];
          const bf16x8 xl0 = *(const bf16x8*)&xs_l[c * 256 + col];
          const bf16x8 xh1 = *(const bf16x8*)&xs_h[(16 + c) * 256 + col];
          const bf16x8 xl1 = *(const bf16x8*)&xs_l[(16 + c) * 256 + col];
          a00 = __builtin_amdgcn_mfma_f32_16x16x32_bf16(xh0, w0h[j], a00, 0, 0, 0);
          a01 = __builtin_amdgcn_mfma_f32_16x16x32_bf16(xh1, w0h[j], a01, 0, 0, 0);
          a10 = __builtin_amdgcn_mfma_f32_16x16x32_bf16(xh0, w1h[j], a10, 0, 0, 0);
          a11 = __builtin_amdgcn_mfma_f32_16x16x32_bf16(xh1, w1h[j], a11, 0, 0, 0);
          a00 = __builtin_amdgcn_mfma_f32_16x16x32_bf16(xh0, w0l[j], a00, 0, 0, 0);
          a01 = __builtin_amdgcn_mfma_f32_16x16x32_bf16(xh1, w0l[j], a01, 0, 0, 0);
          a10 = __builtin_amdgcn_mfma_f32_16x16x32_bf16(xh0, w1l[j], a10, 0, 0, 0);
          a11 = __builtin_amdgcn_mfma_f32_16x16x32_bf16(xh1, w1l[j], a11, 0, 0, 0);
          a00 = __builtin_amdgcn_mfma_f32_16x16x32_bf16(xl0, w0h[j], a00, 0, 0, 0);
          a01 = __builtin_amdgcn_mfma_f32_16x16x32_bf16(xl1, w0h[j], a01, 0, 0, 0);
          a10 = __builtin_amdgcn_mfma_f32_16x16x32_bf16(xl0, w1h[j], a10, 0, 0, 0);
          a11 = __builtin_amdgcn_mfma_f32_16x16x32_bf16(xl1, w1h[j], a11, 0, 0, 0);
        }
      }
#pragma unroll
      for (int i = 0; i < 4; ++i) {
        O[(size_t)(n0 + g * 4 + i) * D_ + dt0 * 16 + c] = f2bf(a00[i]);
        O[(size_t)(n0 + 16 + g * 4 + i) * D_ + dt0 * 16 + c] = f2bf(a01[i]);
        O[(size_t)(n0 + g * 4 + i) * D_ + dt1 * 16 + c] = f2bf(a10[i]);
        O[(size_t)(n0 + 16 + g * 4 + i) * D_ + dt1 * 16 + c] = f2bf(a11[i]);
      }
    }
  } else {
    // V (roles 2,3): 4 dt tiles each, processed in pairs, 4 acc chains
    const size_t wo = (size_t)2 * 32768;
    const int dbase = (role - 2) * 64;
    u16* __restrict__ O = Vt + (size_t)b * D_ * N_;
#pragma unroll 1
    for (int dtg = 0; dtg < 2; ++dtg) {
      f32x4 a00 = {0.f, 0.f, 0.f, 0.f};
      f32x4 a01 = {0.f, 0.f, 0.f, 0.f};
      f32x4 a10 = {0.f, 0.f, 0.f, 0.f};
      f32x4 a11 = {0.f, 0.f, 0.f, 0.f};
      const int dr0 = dbase + dtg * 32, dr1 = dbase + dtg * 32 + 16;
#pragma unroll 1
      for (int kcb = 0; kcb < 2; ++kcb) {
        bf16x8 w0h[4], w0l[4], w1h[4], w1l[4];
#pragma unroll
        for (int j = 0; j < 4; ++j) {
          const size_t o0 =
              wo + (size_t)(dr0 + c) * 256 + (kcb * 4 + j) * 32 + g * 8;
          const size_t o1 =
              wo + (size_t)(dr1 + c) * 256 + (kcb * 4 + j) * 32 + g * 8;
          w0h[j] = *(const bf16x8*)&Whi[o0];
          w0l[j] = *(const bf16x8*)&Wlo[o0];
          w1h[j] = *(const bf16x8*)&Whi[o1];
          w1l[j] = *(const bf16x8*)&Wlo[o1];
        }
#pragma unroll
        for (int j = 0; j < 4; ++j) {
          const int kc = kcb * 4 + j;
          const int col = (kc * 32 + g * 8) ^ ((c & 7) << 3);
          const bf16x8 xh0 = *(const bf16x8*)&xs_h[c * 256 + col];
          const bf16x8 xl0 = *(const bf16x8*)&xs_l[c * 256 + col];
          const bf16x8 xh1 = *(const bf16x8*)&xs_h[(16 + c) * 256 + col];
          const bf16x8 xl1 = *(const bf16x8*)&xs_l[(16 + c) * 256 + col];
          a00 = __builtin_amdgcn_mfma_f32_16x16x32_bf16(w0h[j], xh0, a00, 0, 0, 0);
          a01 = __builtin_amdgcn_mfma_f32_16x16x32_bf16(w0h[j], xh1, a01, 0, 0, 0);
          a10 = __builtin_amdgcn_mfma_f32_16x16x32_bf16(w1h[j], xh0, a10, 0, 0, 0);
          a11 = __builtin_amdgcn_mfma_f32_16x16x32_bf16(w1h[j], xh1, a11, 0, 0, 0);
          a00 = __builtin_amdgcn_mfma_f32_16x16x32_bf16(w0l[j], xh0, a00, 0, 0, 0);
          a01 = __builtin_amdgcn_mfma_f32_16x16x32_bf16(w0l[j], xh1, a01, 0, 0, 0);
          a10 = __builtin_amdgcn_mfma_f32_16x16x32_bf16(w1l[j], xh0, a10, 0, 0, 0);
          a11 = __builtin_amdgcn_mfma_f32_16x16x32_bf16(w1l[j], xh1, a11, 0, 0, 0);
          a00 = __builtin_amdgcn_mfma_f32_16x16x32_bf16(w0h[j], xl0, a00, 0, 0, 0);
          a01 = __builtin_amdgcn_mfma_f32_16x16x32_bf16(w0h[j], xl1, a01, 0, 0, 0);
          a10 = __builtin_amdgcn_mfma_f32_16x16x32_bf16(w1h[j], xl0, a10, 0, 0, 0);
          a11 = __builtin_amdgcn_mfma_f32_16x16x32_bf16(w1h[j], xl1, a11, 0, 0, 0);
        }
      }
#pragma unroll
      for (int i = 0; i < 4; ++i) {
        O[(size_t)(dr0 + g * 4 + i) * N_ + n0 + c] = f2bf(a00[i]);
        O[(size_t)(dr0 + g * 4 + i) * N_ + n0 + 16 + c] = f2bf(a01[i]);
        O[(size_t)(dr1 + g * 4 + i) * N_ + n0 + c] = f2bf(a10[i]);
        O[(size_t)(dr1 + g * 4 + i) * N_ + n0 + 16 + c] = f2bf(a11[i]);
      }
    }
  }
}

// swizzled LDS index helpers (u16 units)
__device__ __forceinline__ int kIdx(int row, int col) {
  return row * 128 + (col ^ ((row & 7) << 3));
}
__device__ __forceinline__ int vIdx(int d, int col) {
  return d * 64 + (col ^ ((d & 7) << 3));
}
// V k-column permutation (validated end-to-end in rounds 6/12-21)
__device__ __forceinline__ int kprm(int q) {
  const int ct = q >> 2, qq = q & 3;
  return ((ct >> 1) << 5) +
         (((qq >> 1) == (ct & 1)) ? (qq << 3) : (((qq ^ 2) << 3) + 4));
}

// -------- flash attention (split-K), 32 q-rows/wave, KVBLK=128 pairs --------
// r21 body (best measured 58.3 us): pair staging + wave-parity slot stagger.
__global__ __launch_bounds__(256, 2) void attn_kernel(
    const u16* __restrict__ Q, const u16* __restrict__ K,
    const u16* __restrict__ Vt, u16* __restrict__ op,
    float* __restrict__ mb, float* __restrict__ lb,
    float* __restrict__ outf, int qt, int rem, int S) {
  __shared__ __align__(16) u16 lds_k[2][64 * 128];   // [slot][kpos][d]
  __shared__ __align__(16) u16 lds_vt[2][128 * 64];  // [slot][d][k']

  const int L = blockIdx.x;
  int qx, b, sid;
  if (((B_ * S) & 7) == 0) {
    const int gpx = (B_ * S) >> 3;
    const int xcd = L & 7, idx = L >> 3;
    const int grp = xcd * gpx + (idx >> 5);
    qx = idx & 31;
    b = grp / S;
    sid = grp - b * S;
  } else {
    qx = L & 31;
    const int r2 = L >> 5;
    b = r2 % B_;
    sid = r2 / B_;
  }
  const int q0 = qx * 128;
  const int NT = qt + (sid < rem ? 1 : 0);  // S in {4,2,1}: NT always even
  const int t0 = sid * qt + (sid < rem ? sid : rem);
  const int k0 = t0 * 64;
  const int t = threadIdx.x;
  const int w = t >> 6, lane = t & 63, g = lane >> 4, c = lane & 15;
  const int qw = q0 + w * 32;
  const bool ghi = (g & 2) != 0;

  const u16* __restrict__ Qb = Q + (size_t)b * N_ * D_;
  const u16* __restrict__ Kb = K + (size_t)b * N_ * D_;
  const u16* __restrict__ Vb = Vt + (size_t)b * D_ * N_;

  bf16x8 qf[2][4];
#pragma unroll
  for (int qh = 0; qh < 2; ++qh)
#pragma unroll
    for (int kc = 0; kc < 4; ++kc)
      qf[qh][kc] =
          *(const bf16x8*)&Qb[(size_t)(qw + qh * 16 + c) * D_ + kc * 32 + g * 8];

  f32x4 acc[8][2];
  f32x4 accl[2];
#pragma unroll
  for (int dt = 0; dt < 8; ++dt)
#pragma unroll
    for (int qh = 0; qh < 2; ++qh) acc[dt][qh] = (f32x4){0.f, 0.f, 0.f, 0.f};
  accl[0] = (f32x4){0.f, 0.f, 0.f, 0.f};
  accl[1] = (f32x4){0.f, 0.f, 0.f, 0.f};
  float mrow[2] = {-3.0e38f, -3.0e38f};
  const float THR = 11.5415603f;  // 8 * log2(e)

  bf16x8 onesv;
#pragma unroll
  for (int j = 0; j < 8; ++j) onesv[j] = (short)0x3F80;

  bf16x8 krg[8], vrg[8];
  auto load_pair = [&](int kbase) {
#pragma unroll
    for (int h = 0; h < 2; ++h)
#pragma unroll
      for (int i = 0; i < 4; ++i) {
        const int idx = i * 256 + t;
        const int kb2 = kbase + h * 64;
        krg[h * 4 + i] =
            *(const bf16x8*)&Kb[(size_t)(kb2 + (idx >> 4)) * D_ + (idx & 15) * 8];
        vrg[h * 4 + i] =
            *(const bf16x8*)&Vb[(size_t)(idx >> 3) * N_ + kb2 + (idx & 7) * 8];
      }
  };
  load_pair(k0);

  auto proc = [&](const u16* kb, const u16* vb) {
    f32x4 s[4][2];
#pragma unroll
    for (int ct = 0; ct < 4; ++ct)
#pragma unroll
      for (int qh = 0; qh < 2; ++qh) s[ct][qh] = (f32x4){0.f, 0.f, 0.f, 0.f};
    __builtin_amdgcn_s_setprio(1);
#pragma unroll
    for (int kc = 0; kc < 4; ++kc) {
#pragma unroll
      for (int ct = 0; ct < 4; ++ct) {
        const bf16x8 kf = *(const bf16x8*)&kb[kIdx(ct * 16 + c, kc * 32 + g * 8)];
        s[ct][0] = __builtin_amdgcn_mfma_f32_16x16x32_bf16(kf, qf[0][kc], s[ct][0], 0, 0, 0);
        s[ct][1] = __builtin_amdgcn_mfma_f32_16x16x32_bf16(kf, qf[1][kc], s[ct][1], 0, 0, 0);
      }
    }
    __builtin_amdgcn_s_setprio(0);

    float pml[2];
#pragma unroll
    for (int qh = 0; qh < 2; ++qh) {
      const float m0 = fmaxf(fmaxf(s[0][qh][0], s[0][qh][1]),
                             fmaxf(s[0][qh][2], s[0][qh][3]));
      const float m1 = fmaxf(fmaxf(s[1][qh][0], s[1][qh][1]),
                             fmaxf(s[1][qh][2], s[1][qh][3]));
      const float m2 = fmaxf(fmaxf(s[2][qh][0], s[2][qh][1]),
                             fmaxf(s[2][qh][2], s[2][qh][3]));
      const float m3 = fmaxf(fmaxf(s[3][qh][0], s[3][qh][1]),
                             fmaxf(s[3][qh][2], s[3][qh][3]));
      pml[qh] = fmaxf(fmaxf(m0, m1), fmaxf(m2, m3));
    }
    const bool need =
        __any((pml[0] > mrow[0] + THR) || (pml[1] > mrow[1] + THR));
    if (need) {
#pragma unroll
      for (int qh = 0; qh < 2; ++qh) {
        float p = pml[qh];
        p = fmaxf(p, __shfl_xor(p, 16));
        p = fmaxf(p, __shfl_xor(p, 32));
        const float mnew = fmaxf(mrow[qh], p);
        const float scl = exp2f(mrow[qh] - mnew);
        mrow[qh] = mnew;
        accl[qh][0] *= scl; accl[qh][1] *= scl;
        accl[qh][2] *= scl; accl[qh][3] *= scl;
#pragma unroll
        for (int dt = 0; dt < 8; ++dt) {
          acc[dt][qh][0] *= scl; acc[dt][qh][1] *= scl;
          acc[dt][qh][2] *= scl; acc[dt][qh][3] *= scl;
        }
      }
    }
#pragma unroll
    for (int qh = 0; qh < 2; ++qh)
#pragma unroll
      for (int ct = 0; ct < 4; ++ct)
#pragma unroll
        for (int i = 0; i < 4; ++i)
          s[ct][qh][i] = exp2f(s[ct][qh][i] - mrow[qh]);

    u32 pfw[2][2][4];
#pragma unroll
    for (int kc = 0; kc < 2; ++kc) {
#pragma unroll
      for (int qh = 0; qh < 2; ++qh) {
        const u32 lo0 = cvt_pk_bf16(s[kc * 2][qh][0], s[kc * 2][qh][1]);
        const u32 lo1 = cvt_pk_bf16(s[kc * 2][qh][2], s[kc * 2][qh][3]);
        const u32 hi0 = cvt_pk_bf16(s[kc * 2 + 1][qh][0], s[kc * 2 + 1][qh][1]);
        const u32 hi1 = cvt_pk_bf16(s[kc * 2 + 1][qh][2], s[kc * 2 + 1][qh][3]);
        pfw[kc][qh][0] = ghi ? hi0 : lo0;
        pfw[kc][qh][1] = ghi ? hi1 : lo1;
        const u32 s0 = ghi ? lo0 : hi0;
        const u32 s1 = ghi ? lo1 : hi1;
        pfw[kc][qh][2] = (u32)__shfl_xor((int)s0, 32);
        pfw[kc][qh][3] = (u32)__shfl_xor((int)s1, 32);
      }
    }

#pragma unroll
    for (int kc = 0; kc < 2; ++kc) {
      union { u32 w2[4]; bf16x8 v; } u0, u1;
#pragma unroll
      for (int j = 0; j < 4; ++j) { u0.w2[j] = pfw[kc][0][j]; u1.w2[j] = pfw[kc][1][j]; }
      __builtin_amdgcn_s_setprio(1);
      accl[0] = __builtin_amdgcn_mfma_f32_16x16x32_bf16(onesv, u0.v, accl[0], 0, 0, 0);
      accl[1] = __builtin_amdgcn_mfma_f32_16x16x32_bf16(onesv, u1.v, accl[1], 0, 0, 0);
#pragma unroll
      for (int dt = 0; dt < 8; ++dt) {
        const bf16x8 vf = *(const bf16x8*)&vb[vIdx(dt * 16 + c, kc * 32 + g * 8)];
        acc[dt][0] = __builtin_amdgcn_mfma_f32_16x16x32_bf16(vf, u0.v, acc[dt][0], 0, 0, 0);
        acc[dt][1] = __builtin_amdgcn_mfma_f32_16x16x32_bf16(vf, u1.v, acc[dt][1], 0, 0, 0);
      }
      __builtin_amdgcn_s_setprio(0);
    }
  };

  for (int kt = 0; kt < NT; kt += 2) {
    __syncthreads();
#pragma unroll
    for (int h = 0; h < 2; ++h)
#pragma unroll
      for (int i = 0; i < 4; ++i) {
        const int idx = i * 256 + t;
        *(bf16x8*)&lds_k[h][kIdx(idx >> 4, (idx & 15) * 8)] = krg[h * 4 + i];
        const int d = idx >> 3, rc = idx & 7;
        const bf16x8 vv = vrg[h * 4 + i];
        s16x4 lo, hi;
        lo[0] = vv[0]; lo[1] = vv[1]; lo[2] = vv[2]; lo[3] = vv[3];
        hi[0] = vv[4]; hi[1] = vv[5]; hi[2] = vv[6]; hi[3] = vv[7];
        *(s16x4*)&lds_vt[h][vIdx(d, kprm(rc * 2))] = lo;
        *(s16x4*)&lds_vt[h][vIdx(d, kprm(rc * 2 + 1))] = hi;
      }
    if (kt + 2 < NT) load_pair(k0 + (kt + 2) * 64);
    __syncthreads();

    // wave-parity slot stagger (slots read-only here; order commutes)
    if (w < 2) {
      proc(&lds_k[0][0], &lds_vt[0][0]);
      proc(&lds_k[1][0], &lds_vt[1][0]);
    } else {
      proc(&lds_k[1][0], &lds_vt[1][0]);
      proc(&lds_k[0][0], &lds_vt[0][0]);
    }
  }

#pragma unroll
  for (int qh = 0; qh < 2; ++qh) {
    const int n = qw + qh * 16 + c;
    const float lr = accl[qh][0];
    if (mb) {
      u16* __restrict__ ob = op + ((size_t)(sid * B_ + b) * D_) * N_;
#pragma unroll
      for (int dt = 0; dt < 8; ++dt)
#pragma unroll
        for (int i = 0; i < 4; ++i)
          ob[(size_t)(dt * 16 + g * 4 + i) * N_ + n] = f2bf(acc[dt][qh][i]);
      if (g == 0) {
        mb[(size_t)(sid * B_ + b) * N_ + n] = mrow[qh];
        lb[(size_t)(sid * B_ + b) * N_ + n] = lr;
      }
    } else {
      const float linv = 1.0f / lr;
      float* __restrict__ ob = outf + (size_t)b * D_ * N_;
#pragma unroll
      for (int dt = 0; dt < 8; ++dt)
#pragma unroll
        for (int i = 0; i < 4; ++i)
          ob[(size_t)(dt * 16 + g * 4 + i) * N_ + n] = acc[dt][qh][i] * linv;
    }
  }
}

// -------- combine split-K partials (bf16, log2-domain stats) -> out ---------
__global__ __launch_bounds__(256) void combine_kernel(
    const u16* __restrict__ op, const float* __restrict__ mbu,
    const float* __restrict__ lbu, float* __restrict__ out, int S) {
  const int idx = blockIdx.x * 256 + threadIdx.x;  // over B*D*(N/4)
  const int n0 = (idx & (N_ / 4 - 1)) * 4;
  const int bd = idx >> 10;
  const int b = bd >> 7, d = bd & (D_ - 1);

  float4 msv[8], lsv[8];
  float M0 = -3e38f, M1 = -3e38f, M2 = -3e38f, M3 = -3e38f;
#pragma unroll
  for (int s = 0; s < 8; ++s)
    if (s < S) {
      msv[s] = *(const float4*)&mbu[(size_t)(s * B_ + b) * N_ + n0];
      lsv[s] = *(const float4*)&lbu[(size_t)(s * B_ + b) * N_ + n0];
      M0 = fmaxf(M0, msv[s].x); M1 = fmaxf(M1, msv[s].y);
      M2 = fmaxf(M2, msv[s].z); M3 = fmaxf(M3, msv[s].w);
    }
  float d0 = 0.f, d1 = 0.f, d2 = 0.f, d3 = 0.f;
  float a0 = 0.f, a1 = 0.f, a2 = 0.f, a3 = 0.f;
#pragma unroll
  for (int s = 0; s < 8; ++s)
    if (s < S) {
      const float w0 = exp2f(msv[s].x - M0);
      const float w1 = exp2f(msv[s].y - M1);
      const float w2 = exp2f(msv[s].z - M2);
      const float w3 = exp2f(msv[s].w - M3);
      d0 += lsv[s].x * w0; d1 += lsv[s].y * w1;
      d2 += lsv[s].z * w2; d3 += lsv[s].w * w3;
      const s16x4 o =
          *(const s16x4*)&op[((size_t)(s * B_ + b) * D_ + d) * N_ + n0];
      a0 += w0 * bf2f((u16)o[0]); a1 += w1 * bf2f((u16)o[1]);
      a2 += w2 * bf2f((u16)o[2]); a3 += w3 * bf2f((u16)o[3]);
    }
  float4 r = {a0 / d0, a1 / d1, a2 / d2, a3 / d3};
  *(float4*)&out[((size_t)b * D_ + d) * N_ + n0] = r;
}

extern "C" void kernel_launch(void* const* d_in, const int* in_sizes, int n_in,
                              void* d_out, int out_size, void* d_ws, size_t ws_size,
                              hipStream_t stream) {
  const float* x  = (const float*)d_in[0];
  const float* Wq = (const float*)d_in[1];
  const float* Wk = (const float*)d_in[2];
  const float* Wv = (const float*)d_in[3];
  float* out = (float*)d_out;

  u16* whi  = (u16*)d_ws;                      // [3][128][256] bf16 hi
  u16* wlo  = whi + (size_t)3 * 128 * 256;     // [3][128][256] bf16 lo
  u16* q_ws = wlo + (size_t)3 * 128 * 256;     // [B][N][D] bf16
  u16* k_ws = q_ws + (size_t)B_ * N_ * D_;     // [B][N][D] bf16
  u16* v_ws = k_ws + (size_t)B_ * N_ * D_;     // [B][D][N] bf16

  castw_kernel<<<96, 256, 0, stream>>>(Wq, Wk, Wv, whi, wlo);
  proj_kernel<<<dim3(N_ / 32, B_), 256, 0, stream>>>(x, whi, wlo, q_ws, k_ws,
                                                     v_ws);

  const size_t baseB =
      ((size_t)6 * 128 * 256 + (size_t)3 * B_ * N_ * D_) * 2;
  // S=4 -> 512 blocks = exactly 2 blocks/CU, NT=16 (even), bijective swizzle
  int S = 0;
  const int cands[3] = {4, 2, 1};
  for (int ci = 0; ci < 3; ++ci) {
    const int cand = cands[ci];
    const size_t need = baseB + (size_t)cand * ((size_t)B_ * D_ * N_ * 2 +
                                                (size_t)2 * B_ * N_ * 4);
    if (ws_size >= need) { S = cand; break; }
  }
  if (S > 1) {
    u16* opb = (u16*)((char*)d_ws + baseB);
    float* mbuf = (float*)(opb + (size_t)S * B_ * D_ * N_);
    float* lbuf = mbuf + (size_t)S * B_ * N_;
    attn_kernel<<<dim3(32 * B_ * S), 256, 0, stream>>>(
        q_ws, k_ws, v_ws, opb, mbuf, lbuf, nullptr, 64 / S, 64 % S, S);
    combine_kernel<<<(B_ * D_ * N_ / 4) / 256, 256, 0, stream>>>(opb, mbuf,
                                                                 lbuf, out, S);
  } else {
    attn_kernel<<<dim3(32 * B_), 256, 0, stream>>>(
        q_ws, k_ws, v_ws, nullptr, nullptr, nullptr, out, 64, 0, 1);
  }
}

// Round 23
// 92.476 us; speedup vs baseline: 1.0515x; 1.0343x over previous
//
#include <hip/hip_runtime.h>
#include <hip/hip_bf16.h>

#define B_ 4
#define C_ 256
#define D_ 128
#define N_ 4096

typedef float f32x4 __attribute__((ext_vector_type(4)));
typedef short bf16x8 __attribute__((ext_vector_type(8)));
typedef short s16x4 __attribute__((ext_vector_type(4)));
typedef unsigned short u16;
typedef unsigned int u32;

__device__ __forceinline__ u16 f2bf(float f) {
  unsigned u = __float_as_uint(f);
  u += 0x7fffu + ((u >> 16) & 1u);
  return (u16)(u >> 16);
}
__device__ __forceinline__ float bf2f(u16 v) {
  return __uint_as_float(((u32)v) << 16);
}
// HW packed f32->bf16 (RNE): a -> low half, b -> high half (validated r8)
__device__ __forceinline__ u32 cvt_pk_bf16(float a, float b) {
  u32 r;
  asm("v_cvt_pk_bf16_f32 %0, %1, %2" : "=v"(r) : "v"(a), "v"(b));
  return r;
}

// ---- W cast: f32 -> hi/lo bf16, FRAGMENT-MAJOR layout; Wq pre-scaled -------
// Fragment (dt,kc,g,c) holds W[dt*16+c][kc*32+g*8 .. +7]; linear index
// fi = ((dt*8+kc)*4+g)*16+c, stored as 8 contiguous u16. A wave's 64 lanes
// (lane = g*16+c) then read 1 KB contiguous per fragment load in proj.
__global__ __launch_bounds__(256) void castw_kernel(
    const float* __restrict__ Wq, const float* __restrict__ Wk,
    const float* __restrict__ Wv, u16* __restrict__ Whi,
    u16* __restrict__ Wlo) {
  const int i = blockIdx.x * 256 + threadIdx.x;  // 12288 fragments
  const int m = i >> 12;                         // 4096 fragments / matrix
  const int fi = i & 4095;
  const int dt = fi >> 9, kc = (fi >> 6) & 7, g = (fi >> 4) & 3, c = fi & 15;
  const float* src = (m == 0) ? Wq : (m == 1) ? Wk : Wv;
  const float scale = (m == 0) ? 1.44269504f : 1.0f;  // fold log2(e) into Q
  const int d = dt * 16 + c, cc = kc * 32 + g * 8;
  const float4 v0 = *(const float4*)(src + d * 256 + cc);
  const float4 v1 = *(const float4*)(src + d * 256 + cc + 4);
  const float vv[8] = {v0.x * scale, v0.y * scale, v0.z * scale, v0.w * scale,
                       v1.x * scale, v1.y * scale, v1.z * scale, v1.w * scale};
  bf16x8 h, l;
#pragma unroll
  for (int k = 0; k < 8; ++k) {
    const u16 hb = f2bf(vv[k]);
    h[k] = (short)hb;
    l[k] = (short)f2bf(vv[k] - bf2f(hb));
  }
  *(bf16x8*)&Whi[(size_t)m * 32768 + fi * 8] = h;
  *(bf16x8*)&Wlo[(size_t)m * 32768 + fi * 8] = l;
}

// fragment offset helper: element index of fragment (dt, j2, g, c)
__device__ __forceinline__ size_t wfrag(int dt, int j2, int g, int c) {
  return (size_t)((((dt * 8 + j2) * 4 + g) * 16 + c) * 8);
}

// ------- projection via 3-term hi/lo MFMA: Q/K -> [N][D], V -> [D][N] -------
// 4 independent accumulator chains (2 dt x 2 nt); per-acc accumulation order
// identical to r17-r22 (bit-identical outputs). W reads fully coalesced via
// fragment-major layout. Role rotated per block (heavy/light SIMD balance).
__global__ __launch_bounds__(256, 2) void proj_kernel(
    const float* __restrict__ x, const u16* __restrict__ Whi,
    const u16* __restrict__ Wlo, u16* __restrict__ Qo, u16* __restrict__ Ko,
    u16* __restrict__ Vt) {
  __shared__ __align__(16) u16 xs_h[32 * 256];  // x^T hi [n][c], swizzled
  __shared__ __align__(16) u16 xs_l[32 * 256];  // x^T lo

  const int n0 = blockIdx.x * 32;
  const int b = blockIdx.y;
  const int t = threadIdx.x;
  const int w = t >> 6, lane = t & 63, g = lane >> 4, c = lane & 15;
  const int role = (w + blockIdx.x) & 3;  // balance heavy/light across SIMDs

  {
    const float* xb = x + ((size_t)b * C_) * N_ + n0;
#pragma unroll
    for (int r = 0; r < 8; ++r) {
      const int id = r * 256 + t;
      const int cr = id >> 3, nq = (id & 7) * 4;
      const float4 v = *(const float4*)(xb + (size_t)cr * N_ + nq);
      const u32 h01 = cvt_pk_bf16(v.x, v.y);
      const u32 h23 = cvt_pk_bf16(v.z, v.w);
      const float r0 = v.x - bf2f((u16)(h01 & 0xffffu));
      const float r1 = v.y - bf2f((u16)(h01 >> 16));
      const float r2 = v.z - bf2f((u16)(h23 & 0xffffu));
      const float r3 = v.w - bf2f((u16)(h23 >> 16));
      const u32 l01 = cvt_pk_bf16(r0, r1);
      const u32 l23 = cvt_pk_bf16(r2, r3);
      const u16 hv[4] = {(u16)(h01 & 0xffffu), (u16)(h01 >> 16),
                         (u16)(h23 & 0xffffu), (u16)(h23 >> 16)};
      const u16 lv[4] = {(u16)(l01 & 0xffffu), (u16)(l01 >> 16),
                         (u16)(l23 & 0xffffu), (u16)(l23 >> 16)};
#pragma unroll
      for (int k2 = 0; k2 < 4; ++k2) {
        const int idx2 = (nq + k2) * 256 + (cr ^ (((nq + k2) & 7) << 3));
        xs_h[idx2] = hv[k2];
        xs_l[idx2] = lv[k2];
      }
    }
  }
  __syncthreads();

  if (role < 2) {
    // Q (role 0) / K (role 1): 8 dt tiles, processed in pairs, 4 acc chains
    const size_t wo = (size_t)role * 32768;
    u16* __restrict__ O = (role == 0 ? Qo : Ko) + (size_t)b * N_ * D_;
#pragma unroll 1
    for (int dtg = 0; dtg < 4; ++dtg) {
      f32x4 a00 = {0.f, 0.f, 0.f, 0.f};  // [dt0][nt0]
      f32x4 a01 = {0.f, 0.f, 0.f, 0.f};  // [dt0][nt1]
      f32x4 a10 = {0.f, 0.f, 0.f, 0.f};  // [dt1][nt0]
      f32x4 a11 = {0.f, 0.f, 0.f, 0.f};  // [dt1][nt1]
      const int dt0 = dtg * 2, dt1 = dtg * 2 + 1;
#pragma unroll 1
      for (int kcb = 0; kcb < 2; ++kcb) {
        bf16x8 w0h[4], w0l[4], w1h[4], w1l[4];
#pragma unroll
        for (int j = 0; j < 4; ++j) {
          const size_t o0 = wo + wfrag(dt0, kcb * 4 + j, g, c);
          const size_t o1 = wo + wfrag(dt1, kcb * 4 + j, g, c);
          w0h[j] = *(const bf16x8*)&Whi[o0];
          w0l[j] = *(const bf16x8*)&Wlo[o0];
          w1h[j] = *(const bf16x8*)&Whi[o1];
          w1l[j] = *(const bf16x8*)&Wlo[o1];
        }
#pragma unroll
        for (int j = 0; j < 4; ++j) {
          const int kc = kcb * 4 + j;
          const int col = (kc * 32 + g * 8) ^ ((c & 7) << 3);
          const bf16x8 xh0 = *(const bf16x8*)&xs_h[c * 256 + col];
          const bf16x8 xl0 = *(const bf16x8*)&xs_l[c * 256 + col];
          const bf16x8 xh1 = *(const bf16x8*)&xs_h[(16 + c) * 256 + col];
          const bf16x8 xl1 = *(const bf16x8*)&xs_l[(16 + c) * 256 + col];
          a00 = __builtin_amdgcn_mfma_f32_16x16x32_bf16(xh0, w0h[j], a00, 0, 0, 0);
          a01 = __builtin_amdgcn_mfma_f32_16x16x32_bf16(xh1, w0h[j], a01, 0, 0, 0);
          a10 = __builtin_amdgcn_mfma_f32_16x16x32_bf16(xh0, w1h[j], a10, 0, 0, 0);
          a11 = __builtin_amdgcn_mfma_f32_16x16x32_bf16(xh1, w1h[j], a11, 0, 0, 0);
          a00 = __builtin_amdgcn_mfma_f32_16x16x32_bf16(xh0, w0l[j], a00, 0, 0, 0);
          a01 = __builtin_amdgcn_mfma_f32_16x16x32_bf16(xh1, w0l[j], a01, 0, 0, 0);
          a10 = __builtin_amdgcn_mfma_f32_16x16x32_bf16(xh0, w1l[j], a10, 0, 0, 0);
          a11 = __builtin_amdgcn_mfma_f32_16x16x32_bf16(xh1, w1l[j], a11, 0, 0, 0);
          a00 = __builtin_amdgcn_mfma_f32_16x16x32_bf16(xl0, w0h[j], a00, 0, 0, 0);
          a01 = __builtin_amdgcn_mfma_f32_16x16x32_bf16(xl1, w0h[j], a01, 0, 0, 0);
          a10 = __builtin_amdgcn_mfma_f32_16x16x32_bf16(xl0, w1h[j], a10, 0, 0, 0);
          a11 = __builtin_amdgcn_mfma_f32_16x16x32_bf16(xl1, w1h[j], a11, 0, 0, 0);
        }
      }
#pragma unroll
      for (int i = 0; i < 4; ++i) {
        O[(size_t)(n0 + g * 4 + i) * D_ + dt0 * 16 + c] = f2bf(a00[i]);
        O[(size_t)(n0 + 16 + g * 4 + i) * D_ + dt0 * 16 + c] = f2bf(a01[i]);
        O[(size_t)(n0 + g * 4 + i) * D_ + dt1 * 16 + c] = f2bf(a10[i]);
        O[(size_t)(n0 + 16 + g * 4 + i) * D_ + dt1 * 16 + c] = f2bf(a11[i]);
      }
    }
  } else {
    // V (roles 2,3): 4 dt tiles each, processed in pairs, 4 acc chains
    const size_t wo = (size_t)2 * 32768;
    const int dtb = (role - 2) * 4;  // dt base within W_v (rows /16)
    u16* __restrict__ O = Vt + (size_t)b * D_ * N_;
#pragma unroll 1
    for (int dtg = 0; dtg < 2; ++dtg) {
      f32x4 a00 = {0.f, 0.f, 0.f, 0.f};
      f32x4 a01 = {0.f, 0.f, 0.f, 0.f};
      f32x4 a10 = {0.f, 0.f, 0.f, 0.f};
      f32x4 a11 = {0.f, 0.f, 0.f, 0.f};
      const int dtv0 = dtb + dtg * 2, dtv1 = dtb + dtg * 2 + 1;
      const int dr0 = dtv0 * 16, dr1 = dtv1 * 16;
#pragma unroll 1
      for (int kcb = 0; kcb < 2; ++kcb) {
        bf16x8 w0h[4], w0l[4], w1h[4], w1l[4];
#pragma unroll
        for (int j = 0; j < 4; ++j) {
          const size_t o0 = wo + wfrag(dtv0, kcb * 4 + j, g, c);
          const size_t o1 = wo + wfrag(dtv1, kcb * 4 + j, g, c);
          w0h[j] = *(const bf16x8*)&Whi[o0];
          w0l[j] = *(const bf16x8*)&Wlo[o0];
          w1h[j] = *(const bf16x8*)&Whi[o1];
          w1l[j] = *(const bf16x8*)&Wlo[o1];
        }
#pragma unroll
        for (int j = 0; j < 4; ++j) {
          const int kc = kcb * 4 + j;
          const int col = (kc * 32 + g * 8) ^ ((c & 7) << 3);
          const bf16x8 xh0 = *(const bf16x8*)&xs_h[c * 256 + col];
          const bf16x8 xl0 = *(const bf16x8*)&xs_l[c * 256 + col];
          const bf16x8 xh1 = *(const bf16x8*)&xs_h[(16 + c) * 256 + col];
          const bf16x8 xl1 = *(const bf16x8*)&xs_l[(16 + c) * 256 + col];
          a00 = __builtin_amdgcn_mfma_f32_16x16x32_bf16(w0h[j], xh0, a00, 0, 0, 0);
          a01 = __builtin_amdgcn_mfma_f32_16x16x32_bf16(w0h[j], xh1, a01, 0, 0, 0);
          a10 = __builtin_amdgcn_mfma_f32_16x16x32_bf16(w1h[j], xh0, a10, 0, 0, 0);
          a11 = __builtin_amdgcn_mfma_f32_16x16x32_bf16(w1h[j], xh1, a11, 0, 0, 0);
          a00 = __builtin_amdgcn_mfma_f32_16x16x32_bf16(w0l[j], xh0, a00, 0, 0, 0);
          a01 = __builtin_amdgcn_mfma_f32_16x16x32_bf16(w0l[j], xh1, a01, 0, 0, 0);
          a10 = __builtin_amdgcn_mfma_f32_16x16x32_bf16(w1l[j], xh0, a10, 0, 0, 0);
          a11 = __builtin_amdgcn_mfma_f32_16x16x32_bf16(w1l[j], xh1, a11, 0, 0, 0);
          a00 = __builtin_amdgcn_mfma_f32_16x16x32_bf16(w0h[j], xl0, a00, 0, 0, 0);
          a01 = __builtin_amdgcn_mfma_f32_16x16x32_bf16(w0h[j], xl1, a01, 0, 0, 0);
          a10 = __builtin_amdgcn_mfma_f32_16x16x32_bf16(w1h[j], xl0, a10, 0, 0, 0);
          a11 = __builtin_amdgcn_mfma_f32_16x16x32_bf16(w1h[j], xl1, a11, 0, 0, 0);
        }
      }
#pragma unroll
      for (int i = 0; i < 4; ++i) {
        O[(size_t)(dr0 + g * 4 + i) * N_ + n0 + c] = f2bf(a00[i]);
        O[(size_t)(dr0 + g * 4 + i) * N_ + n0 + 16 + c] = f2bf(a01[i]);
        O[(size_t)(dr1 + g * 4 + i) * N_ + n0 + c] = f2bf(a10[i]);
        O[(size_t)(dr1 + g * 4 + i) * N_ + n0 + 16 + c] = f2bf(a11[i]);
      }
    }
  }
}

// swizzled LDS index helpers (u16 units)
__device__ __forceinline__ int kIdx(int row, int col) {
  return row * 128 + (col ^ ((row & 7) << 3));
}
__device__ __forceinline__ int vIdx(int d, int col) {
  return d * 64 + (col ^ ((d & 7) << 3));
}
// V k-column permutation (validated end-to-end in rounds 6/12-22)
__device__ __forceinline__ int kprm(int q) {
  const int ct = q >> 2, qq = q & 3;
  return ((ct >> 1) << 5) +
         (((qq >> 1) == (ct & 1)) ? (qq << 3) : (((qq ^ 2) << 3) + 4));
}

// -------- flash attention (split-K), 32 q-rows/wave, KVBLK=128 pairs --------
// r21/r22 body (best measured 58.3 us): pair staging + wave-parity stagger.
__global__ __launch_bounds__(256, 2) void attn_kernel(
    const u16* __restrict__ Q, const u16* __restrict__ K,
    const u16* __restrict__ Vt, u16* __restrict__ op,
    float* __restrict__ mb, float* __restrict__ lb,
    float* __restrict__ outf, int qt, int rem, int S) {
  __shared__ __align__(16) u16 lds_k[2][64 * 128];   // [slot][kpos][d]
  __shared__ __align__(16) u16 lds_vt[2][128 * 64];  // [slot][d][k']

  const int L = blockIdx.x;
  int qx, b, sid;
  if (((B_ * S) & 7) == 0) {
    const int gpx = (B_ * S) >> 3;
    const int xcd = L & 7, idx = L >> 3;
    const int grp = xcd * gpx + (idx >> 5);
    qx = idx & 31;
    b = grp / S;
    sid = grp - b * S;
  } else {
    qx = L & 31;
    const int r2 = L >> 5;
    b = r2 % B_;
    sid = r2 / B_;
  }
  const int q0 = qx * 128;
  const int NT = qt + (sid < rem ? 1 : 0);  // S in {4,2,1}: NT always even
  const int t0 = sid * qt + (sid < rem ? sid : rem);
  const int k0 = t0 * 64;
  const int t = threadIdx.x;
  const int w = t >> 6, lane = t & 63, g = lane >> 4, c = lane & 15;
  const int qw = q0 + w * 32;
  const bool ghi = (g & 2) != 0;

  const u16* __restrict__ Qb = Q + (size_t)b * N_ * D_;
  const u16* __restrict__ Kb = K + (size_t)b * N_ * D_;
  const u16* __restrict__ Vb = Vt + (size_t)b * D_ * N_;

  bf16x8 qf[2][4];
#pragma unroll
  for (int qh = 0; qh < 2; ++qh)
#pragma unroll
    for (int kc = 0; kc < 4; ++kc)
      qf[qh][kc] =
          *(const bf16x8*)&Qb[(size_t)(qw + qh * 16 + c) * D_ + kc * 32 + g * 8];

  f32x4 acc[8][2];
  f32x4 accl[2];
#pragma unroll
  for (int dt = 0; dt < 8; ++dt)
#pragma unroll
    for (int qh = 0; qh < 2; ++qh) acc[dt][qh] = (f32x4){0.f, 0.f, 0.f, 0.f};
  accl[0] = (f32x4){0.f, 0.f, 0.f, 0.f};
  accl[1] = (f32x4){0.f, 0.f, 0.f, 0.f};
  float mrow[2] = {-3.0e38f, -3.0e38f};
  const float THR = 11.5415603f;  // 8 * log2(e)

  bf16x8 onesv;
#pragma unroll
  for (int j = 0; j < 8; ++j) onesv[j] = (short)0x3F80;

  bf16x8 krg[8], vrg[8];
  auto load_pair = [&](int kbase) {
#pragma unroll
    for (int h = 0; h < 2; ++h)
#pragma unroll
      for (int i = 0; i < 4; ++i) {
        const int idx = i * 256 + t;
        const int kb2 = kbase + h * 64;
        krg[h * 4 + i] =
            *(const bf16x8*)&Kb[(size_t)(kb2 + (idx >> 4)) * D_ + (idx & 15) * 8];
        vrg[h * 4 + i] =
            *(const bf16x8*)&Vb[(size_t)(idx >> 3) * N_ + kb2 + (idx & 7) * 8];
      }
  };
  load_pair(k0);

  auto proc = [&](const u16* kb, const u16* vb) {
    f32x4 s[4][2];
#pragma unroll
    for (int ct = 0; ct < 4; ++ct)
#pragma unroll
      for (int qh = 0; qh < 2; ++qh) s[ct][qh] = (f32x4){0.f, 0.f, 0.f, 0.f};
    __builtin_amdgcn_s_setprio(1);
#pragma unroll
    for (int kc = 0; kc < 4; ++kc) {
#pragma unroll
      for (int ct = 0; ct < 4; ++ct) {
        const bf16x8 kf = *(const bf16x8*)&kb[kIdx(ct * 16 + c, kc * 32 + g * 8)];
        s[ct][0] = __builtin_amdgcn_mfma_f32_16x16x32_bf16(kf, qf[0][kc], s[ct][0], 0, 0, 0);
        s[ct][1] = __builtin_amdgcn_mfma_f32_16x16x32_bf16(kf, qf[1][kc], s[ct][1], 0, 0, 0);
      }
    }
    __builtin_amdgcn_s_setprio(0);

    float pml[2];
#pragma unroll
    for (int qh = 0; qh < 2; ++qh) {
      const float m0 = fmaxf(fmaxf(s[0][qh][0], s[0][qh][1]),
                             fmaxf(s[0][qh][2], s[0][qh][3]));
      const float m1 = fmaxf(fmaxf(s[1][qh][0], s[1][qh][1]),
                             fmaxf(s[1][qh][2], s[1][qh][3]));
      const float m2 = fmaxf(fmaxf(s[2][qh][0], s[2][qh][1]),
                             fmaxf(s[2][qh][2], s[2][qh][3]));
      const float m3 = fmaxf(fmaxf(s[3][qh][0], s[3][qh][1]),
                             fmaxf(s[3][qh][2], s[3][qh][3]));
      pml[qh] = fmaxf(fmaxf(m0, m1), fmaxf(m2, m3));
    }
    const bool need =
        __any((pml[0] > mrow[0] + THR) || (pml[1] > mrow[1] + THR));
    if (need) {
#pragma unroll
      for (int qh = 0; qh < 2; ++qh) {
        float p = pml[qh];
        p = fmaxf(p, __shfl_xor(p, 16));
        p = fmaxf(p, __shfl_xor(p, 32));
        const float mnew = fmaxf(mrow[qh], p);
        const float scl = exp2f(mrow[qh] - mnew);
        mrow[qh] = mnew;
        accl[qh][0] *= scl; accl[qh][1] *= scl;
        accl[qh][2] *= scl; accl[qh][3] *= scl;
#pragma unroll
        for (int dt = 0; dt < 8; ++dt) {
          acc[dt][qh][0] *= scl; acc[dt][qh][1] *= scl;
          acc[dt][qh][2] *= scl; acc[dt][qh][3] *= scl;
        }
      }
    }
#pragma unroll
    for (int qh = 0; qh < 2; ++qh)
#pragma unroll
      for (int ct = 0; ct < 4; ++ct)
#pragma unroll
        for (int i = 0; i < 4; ++i)
          s[ct][qh][i] = exp2f(s[ct][qh][i] - mrow[qh]);

    u32 pfw[2][2][4];
#pragma unroll
    for (int kc = 0; kc < 2; ++kc) {
#pragma unroll
      for (int qh = 0; qh < 2; ++qh) {
        const u32 lo0 = cvt_pk_bf16(s[kc * 2][qh][0], s[kc * 2][qh][1]);
        const u32 lo1 = cvt_pk_bf16(s[kc * 2][qh][2], s[kc * 2][qh][3]);
        const u32 hi0 = cvt_pk_bf16(s[kc * 2 + 1][qh][0], s[kc * 2 + 1][qh][1]);
        const u32 hi1 = cvt_pk_bf16(s[kc * 2 + 1][qh][2], s[kc * 2 + 1][qh][3]);
        pfw[kc][qh][0] = ghi ? hi0 : lo0;
        pfw[kc][qh][1] = ghi ? hi1 : lo1;
        const u32 s0 = ghi ? lo0 : hi0;
        const u32 s1 = ghi ? lo1 : hi1;
        pfw[kc][qh][2] = (u32)__shfl_xor((int)s0, 32);
        pfw[kc][qh][3] = (u32)__shfl_xor((int)s1, 32);
      }
    }

#pragma unroll
    for (int kc = 0; kc < 2; ++kc) {
      union { u32 w2[4]; bf16x8 v; } u0, u1;
#pragma unroll
      for (int j = 0; j < 4; ++j) { u0.w2[j] = pfw[kc][0][j]; u1.w2[j] = pfw[kc][1][j]; }
      __builtin_amdgcn_s_setprio(1);
      accl[0] = __builtin_amdgcn_mfma_f32_16x16x32_bf16(onesv, u0.v, accl[0], 0, 0, 0);
      accl[1] = __builtin_amdgcn_mfma_f32_16x16x32_bf16(onesv, u1.v, accl[1], 0, 0, 0);
#pragma unroll
      for (int dt = 0; dt < 8; ++dt) {
        const bf16x8 vf = *(const bf16x8*)&vb[vIdx(dt * 16 + c, kc * 32 + g * 8)];
        acc[dt][0] = __builtin_amdgcn_mfma_f32_16x16x32_bf16(vf, u0.v, acc[dt][0], 0, 0, 0);
        acc[dt][1] = __builtin_amdgcn_mfma_f32_16x16x32_bf16(vf, u1.v, acc[dt][1], 0, 0, 0);
      }
      __builtin_amdgcn_s_setprio(0);
    }
  };

  for (int kt = 0; kt < NT; kt += 2) {
    __syncthreads();
#pragma unroll
    for (int h = 0; h < 2; ++h)
#pragma unroll
      for (int i = 0; i < 4; ++i) {
        const int idx = i * 256 + t;
        *(bf16x8*)&lds_k[h][kIdx(idx >> 4, (idx & 15) * 8)] = krg[h * 4 + i];
        const int d = idx >> 3, rc = idx & 7;
        const bf16x8 vv = vrg[h * 4 + i];
        s16x4 lo, hi;
        lo[0] = vv[0]; lo[1] = vv[1]; lo[2] = vv[2]; lo[3] = vv[3];
        hi[0] = vv[4]; hi[1] = vv[5]; hi[2] = vv[6]; hi[3] = vv[7];
        *(s16x4*)&lds_vt[h][vIdx(d, kprm(rc * 2))] = lo;
        *(s16x4*)&lds_vt[h][vIdx(d, kprm(rc * 2 + 1))] = hi;
      }
    if (kt + 2 < NT) load_pair(k0 + (kt + 2) * 64);
    __syncthreads();

    // wave-parity slot stagger (slots read-only here; order commutes)
    if (w < 2) {
      proc(&lds_k[0][0], &lds_vt[0][0]);
      proc(&lds_k[1][0], &lds_vt[1][0]);
    } else {
      proc(&lds_k[1][0], &lds_vt[1][0]);
      proc(&lds_k[0][0], &lds_vt[0][0]);
    }
  }

#pragma unroll
  for (int qh = 0; qh < 2; ++qh) {
    const int n = qw + qh * 16 + c;
    const float lr = accl[qh][0];
    if (mb) {
      u16* __restrict__ ob = op + ((size_t)(sid * B_ + b) * D_) * N_;
#pragma unroll
      for (int dt = 0; dt < 8; ++dt)
#pragma unroll
        for (int i = 0; i < 4; ++i)
          ob[(size_t)(dt * 16 + g * 4 + i) * N_ + n] = f2bf(acc[dt][qh][i]);
      if (g == 0) {
        mb[(size_t)(sid * B_ + b) * N_ + n] = mrow[qh];
        lb[(size_t)(sid * B_ + b) * N_ + n] = lr;
      }
    } else {
      const float linv = 1.0f / lr;
      float* __restrict__ ob = outf + (size_t)b * D_ * N_;
#pragma unroll
      for (int dt = 0; dt < 8; ++dt)
#pragma unroll
        for (int i = 0; i < 4; ++i)
          ob[(size_t)(dt * 16 + g * 4 + i) * N_ + n] = acc[dt][qh][i] * linv;
    }
  }
}

// -------- combine split-K partials (bf16, log2-domain stats) -> out ---------
__global__ __launch_bounds__(256) void combine_kernel(
    const u16* __restrict__ op, const float* __restrict__ mbu,
    const float* __restrict__ lbu, float* __restrict__ out, int S) {
  const int idx = blockIdx.x * 256 + threadIdx.x;  // over B*D*(N/4)
  const int n0 = (idx & (N_ / 4 - 1)) * 4;
  const int bd = idx >> 10;
  const int b = bd >> 7, d = bd & (D_ - 1);

  float4 msv[8], lsv[8];
  float M0 = -3e38f, M1 = -3e38f, M2 = -3e38f, M3 = -3e38f;
#pragma unroll
  for (int s = 0; s < 8; ++s)
    if (s < S) {
      msv[s] = *(const float4*)&mbu[(size_t)(s * B_ + b) * N_ + n0];
      lsv[s] = *(const float4*)&lbu[(size_t)(s * B_ + b) * N_ + n0];
      M0 = fmaxf(M0, msv[s].x); M1 = fmaxf(M1, msv[s].y);
      M2 = fmaxf(M2, msv[s].z); M3 = fmaxf(M3, msv[s].w);
    }
  float d0 = 0.f, d1 = 0.f, d2 = 0.f, d3 = 0.f;
  float a0 = 0.f, a1 = 0.f, a2 = 0.f, a3 = 0.f;
#pragma unroll
  for (int s = 0; s < 8; ++s)
    if (s < S) {
      const float w0 = exp2f(msv[s].x - M0);
      const float w1 = exp2f(msv[s].y - M1);
      const float w2 = exp2f(msv[s].z - M2);
      const float w3 = exp2f(msv[s].w - M3);
      d0 += lsv[s].x * w0; d1 += lsv[s].y * w1;
      d2 += lsv[s].z * w2; d3 += lsv[s].w * w3;
      const s16x4 o =
          *(const s16x4*)&op[((size_t)(s * B_ + b) * D_ + d) * N_ + n0];
      a0 += w0 * bf2f((u16)o[0]); a1 += w1 * bf2f((u16)o[1]);
      a2 += w2 * bf2f((u16)o[2]); a3 += w3 * bf2f((u16)o[3]);
    }
  float4 r = {a0 / d0, a1 / d1, a2 / d2, a3 / d3};
  *(float4*)&out[((size_t)b * D_ + d) * N_ + n0] = r;
}

extern "C" void kernel_launch(void* const* d_in, const int* in_sizes, int n_in,
                              void* d_out, int out_size, void* d_ws, size_t ws_size,
                              hipStream_t stream) {
  const float* x  = (const float*)d_in[0];
  const float* Wq = (const float*)d_in[1];
  const float* Wk = (const float*)d_in[2];
  const float* Wv = (const float*)d_in[3];
  float* out = (float*)d_out;

  u16* whi  = (u16*)d_ws;                      // [3][4096 frags][8] bf16 hi
  u16* wlo  = whi + (size_t)3 * 128 * 256;     // [3][4096 frags][8] bf16 lo
  u16* q_ws = wlo + (size_t)3 * 128 * 256;     // [B][N][D] bf16
  u16* k_ws = q_ws + (size_t)B_ * N_ * D_;     // [B][N][D] bf16
  u16* v_ws = k_ws + (size_t)B_ * N_ * D_;     // [B][D][N] bf16

  castw_kernel<<<48, 256, 0, stream>>>(Wq, Wk, Wv, whi, wlo);
  proj_kernel<<<dim3(N_ / 32, B_), 256, 0, stream>>>(x, whi, wlo, q_ws, k_ws,
                                                     v_ws);

  const size_t baseB =
      ((size_t)6 * 128 * 256 + (size_t)3 * B_ * N_ * D_) * 2;
  // S=4 -> 512 blocks = exactly 2 blocks/CU, NT=16 (even), bijective swizzle
  int S = 0;
  const int cands[3] = {4, 2, 1};
  for (int ci = 0; ci < 3; ++ci) {
    const int cand = cands[ci];
    const size_t need = baseB + (size_t)cand * ((size_t)B_ * D_ * N_ * 2 +
                                                (size_t)2 * B_ * N_ * 4);
    if (ws_size >= need) { S = cand; break; }
  }
  if (S > 1) {
    u16* opb = (u16*)((char*)d_ws + baseB);
    float* mbuf = (float*)(opb + (size_t)S * B_ * D_ * N_);
    float* lbuf = mbuf + (size_t)S * B_ * N_;
    attn_kernel<<<dim3(32 * B_ * S), 256, 0, stream>>>(
        q_ws, k_ws, v_ws, opb, mbuf, lbuf, nullptr, 64 / S, 64 % S, S);
    combine_kernel<<<(B_ * D_ * N_ / 4) / 256, 256, 0, stream>>>(opb, mbuf,
                                                                 lbuf, out, S);
  } else {
    attn_kernel<<<dim3(32 * B_), 256, 0, stream>>>(
        q_ws, k_ws, v_ws, nullptr, nullptr, nullptr, out, 64, 0, 1);
  }
}